// Round 1
// baseline (4803.843 us; speedup 1.0000x reference)
//
#include <hip/hip_runtime.h>
#include <hip/hip_bf16.h>

#define N_NODES 100000
#define N_EDGES 320000
#define HID 256
#define NE 128
#define NLAYERS 3

// ---------------------------------------------------------------------------
// Init: x[n, 0:128] = node_emb[type]; x[n, 128:256] = per-type attr embedding
// ---------------------------------------------------------------------------
__global__ __launch_bounds__(256) void k_init(
    const float* __restrict__ node_attr,  // [N,17]
    const float* __restrict__ node_emb,   // [4,128]
    const float* __restrict__ net_W, const float* __restrict__ net_b,
    const float* __restrict__ dev_W, const float* __restrict__ dev_b,
    const float* __restrict__ pin_emb,    // [17,128]
    const int*   __restrict__ node_type,
    float* __restrict__ x)                // [N,256]
{
    int t = blockIdx.x * 256 + threadIdx.x;
    if (t >= N_NODES * NE) return;
    int n = t >> 7;          // 128 threads per node -> wave-uniform n
    int c = t & 127;
    int ty = node_type[n];
    float emb = node_emb[ty * NE + c];
    float a;
    if (ty == 0 || ty == 1) {
        const float* W = (ty == 0) ? net_W : net_b == dev_b ? dev_W : dev_W; // (keep simple)
        const float* b = (ty == 0) ? net_b : dev_b;
        W = (ty == 0) ? net_W : dev_W;
        float s = b[c];
        const float* ar = node_attr + (size_t)n * 17;
        #pragma unroll
        for (int k = 0; k < 17; ++k) s += ar[k] * W[k * NE + c];
        a = s;
    } else if (ty == 2) {
        int idx = (int)node_attr[(size_t)n * 17];  // uniform[0,1) -> 0
        a = pin_emb[idx * NE + c];
    } else {
        a = 0.0f;
    }
    x[(size_t)n * HID + c]      = emb;
    x[(size_t)n * HID + NE + c] = a;
}

// ---------------------------------------------------------------------------
// Edge in-degree count (float)
// ---------------------------------------------------------------------------
__global__ __launch_bounds__(256) void k_count(
    const int* __restrict__ edge_index, float* __restrict__ cnt)
{
    int e = blockIdx.x * 256 + threadIdx.x;
    if (e < N_EDGES) atomicAdd(&cnt[edge_index[N_EDGES + e]], 1.0f);
}

// ---------------------------------------------------------------------------
// Scatter-add: agg[dst] += x[src].  One 64-lane wave per edge, float4/lane.
// ---------------------------------------------------------------------------
__global__ __launch_bounds__(256) void k_scatter(
    const float* __restrict__ x, const int* __restrict__ edge_index,
    float* __restrict__ agg)
{
    int g = blockIdx.x * 256 + threadIdx.x;
    int e = g >> 6;
    if (e >= N_EDGES) return;
    int lane = g & 63;
    int s = edge_index[e];
    int d = edge_index[N_EDGES + e];
    float4 v = *(const float4*)(x + (size_t)s * HID + lane * 4);
    float* o = agg + (size_t)d * HID + lane * 4;
    atomicAdd(o + 0, v.x);
    atomicAdd(o + 1, v.y);
    atomicAdd(o + 2, v.z);
    atomicAdd(o + 3, v.w);
}

// ---------------------------------------------------------------------------
// Fused layer GEMM.
//   SAGE:  out = relu( (A/denom) @ W1m + bias + X @ W2m )   (out may alias A)
//   HEAD:  out = relu( X @ W1m + bias )
// Block: 256 threads -> 64 rows x 256 cols.  Thread: 8 rows x 8 cols.
// ---------------------------------------------------------------------------
#define BM 64
#define BK 16

template <bool SAGE>
__global__ __launch_bounds__(256) void k_layer(
    const float* __restrict__ A,     // agg rows (SAGE only)
    const float* __restrict__ X,     // x rows
    const float* __restrict__ cnt,   // in-degree (SAGE only)
    const float* __restrict__ W1m,   // Wl or W0   [256,256]
    const float* __restrict__ bias,  // [256]
    const float* __restrict__ W2m,   // Wr (SAGE only)
    float* __restrict__ out)
{
    __shared__ float As[BM * BK];
    __shared__ float Ws[BK * HID];

    const int tid = threadIdx.x;
    const int r0  = blockIdx.x * BM;
    const int tx  = tid & 31;   // col group: cols tx + 32*j
    const int ty  = tid >> 5;   // row group: rows ty*8 + i

    float acc[8][8];
    #pragma unroll
    for (int i = 0; i < 8; ++i)
        #pragma unroll
        for (int j = 0; j < 8; ++j) acc[i][j] = 0.0f;

    const int ldrow = tid >> 2;          // staging: 4 threads per row
    const int ldk   = (tid & 3) * 4;
    int ldgr = r0 + ldrow; if (ldgr >= N_NODES) ldgr = N_NODES - 1; // clamp stays in-block
    const int wk  = tid >> 4;            // staging: 16 threads per k-row
    const int wcs = (tid & 15) * 16;

    const int npass = SAGE ? 2 : 1;
    for (int p = 0; p < npass; ++p) {
        const float* src = (SAGE && p == 0) ? A : X;
        const float* W   = (p == 0) ? W1m : W2m;
        for (int k0 = 0; k0 < HID; k0 += BK) {
            __syncthreads();
            { // stage A-tile [64][16]
                float4 v = *(const float4*)(src + (size_t)ldgr * HID + k0 + ldk);
                As[ldrow * BK + ldk + 0] = v.x;
                As[ldrow * BK + ldk + 1] = v.y;
                As[ldrow * BK + ldk + 2] = v.z;
                As[ldrow * BK + ldk + 3] = v.w;
            }
            { // stage W-tile [16][256]
                const float* wp = W + (size_t)(k0 + wk) * HID + wcs;
                float* dp = &Ws[wk * HID + wcs];
                *(float4*)(dp + 0)  = *(const float4*)(wp + 0);
                *(float4*)(dp + 4)  = *(const float4*)(wp + 4);
                *(float4*)(dp + 8)  = *(const float4*)(wp + 8);
                *(float4*)(dp + 12) = *(const float4*)(wp + 12);
            }
            __syncthreads();
            #pragma unroll
            for (int k = 0; k < BK; ++k) {
                float av[8], bv[8];
                #pragma unroll
                for (int i = 0; i < 8; ++i) av[i] = As[(ty * 8 + i) * BK + k];
                #pragma unroll
                for (int j = 0; j < 8; ++j) bv[j] = Ws[k * HID + tx + 32 * j];
                #pragma unroll
                for (int i = 0; i < 8; ++i)
                    #pragma unroll
                    for (int j = 0; j < 8; ++j) acc[i][j] += av[i] * bv[j];
            }
        }
        if (SAGE && p == 0) {
            // fold in 1/denom (row scale commutes with matmul), then bias
            #pragma unroll
            for (int i = 0; i < 8; ++i) {
                int gr = r0 + ty * 8 + i; if (gr >= N_NODES) gr = N_NODES - 1;
                float rs = 1.0f / fmaxf(cnt[gr], 1.0f);
                #pragma unroll
                for (int j = 0; j < 8; ++j) acc[i][j] *= rs;
            }
            #pragma unroll
            for (int j = 0; j < 8; ++j) {
                float bv = bias[tx + 32 * j];
                #pragma unroll
                for (int i = 0; i < 8; ++i) acc[i][j] += bv;
            }
        }
    }
    if (!SAGE) {
        #pragma unroll
        for (int j = 0; j < 8; ++j) {
            float bv = bias[tx + 32 * j];
            #pragma unroll
            for (int i = 0; i < 8; ++i) acc[i][j] += bv;
        }
    }
    #pragma unroll
    for (int i = 0; i < 8; ++i) {
        int gr = r0 + ty * 8 + i;
        if (gr < N_NODES) {
            float* op = out + (size_t)gr * HID;
            #pragma unroll
            for (int j = 0; j < 8; ++j)
                op[tx + 32 * j] = fmaxf(acc[i][j], 0.0f);
        }
    }
}

// ---------------------------------------------------------------------------
// pred[n] = b1 + sum_c h[n,c] * W1[c].  One wave per node.
// ---------------------------------------------------------------------------
__global__ __launch_bounds__(256) void k_pred(
    const float* __restrict__ H, const float* __restrict__ W1,
    const float* __restrict__ b1, float* __restrict__ out)
{
    int g = blockIdx.x * 256 + threadIdx.x;
    int n = g >> 6;
    if (n >= N_NODES) return;
    int lane = g & 63;
    float4 h = *(const float4*)(H + (size_t)n * HID + lane * 4);
    float4 w = *(const float4*)(W1 + lane * 4);
    float s = h.x * w.x + h.y * w.y + h.z * w.z + h.w * w.w;
    #pragma unroll
    for (int o = 32; o > 0; o >>= 1) s += __shfl_down(s, o, 64);
    if (lane == 0) out[n] = s + b1[0];
}

// ---------------------------------------------------------------------------
// true_class = trunc(y[:,1]); true_label = y
// ---------------------------------------------------------------------------
__global__ __launch_bounds__(256) void k_tail(
    const float* __restrict__ y, float* __restrict__ out)
{
    int i = blockIdx.x * 256 + threadIdx.x;
    if (i >= N_NODES) return;
    float y0 = y[(size_t)i * 2 + 0];
    float y1 = y[(size_t)i * 2 + 1];
    out[N_NODES + i] = (float)(int)y1;
    out[2 * N_NODES + 2 * i + 0] = y0;
    out[2 * N_NODES + 2 * i + 1] = y1;
}

extern "C" void kernel_launch(void* const* d_in, const int* in_sizes, int n_in,
                              void* d_out, int out_size, void* d_ws, size_t ws_size,
                              hipStream_t stream) {
    const float* node_attr = (const float*)d_in[0];
    const float* y         = (const float*)d_in[1];
    const float* node_emb  = (const float*)d_in[2];
    const float* net_W     = (const float*)d_in[4];
    const float* net_b     = (const float*)d_in[5];
    const float* dev_W     = (const float*)d_in[6];
    const float* dev_b     = (const float*)d_in[7];
    const float* pin_emb   = (const float*)d_in[8];
    const float* sage_Wl   = (const float*)d_in[9];
    const float* sage_bl   = (const float*)d_in[10];
    const float* sage_Wr   = (const float*)d_in[11];
    const float* head_W0   = (const float*)d_in[12];
    const float* head_b0   = (const float*)d_in[13];
    const float* head_W1   = (const float*)d_in[14];
    const float* head_b1   = (const float*)d_in[15];
    const int*   node_type = (const int*)d_in[16];
    const int*   edge_idx  = (const int*)d_in[18];
    float* out = (float*)d_out;

    const size_t xelems = (size_t)N_NODES * HID;
    float* buf0 = (float*)d_ws;
    float* buf1 = buf0 + xelems;
    float* cnt  = buf1 + xelems;

    hipMemsetAsync(cnt, 0, N_NODES * sizeof(float), stream);
    k_init<<<(N_NODES * NE + 255) / 256, 256, 0, stream>>>(
        node_attr, node_emb, net_W, net_b, dev_W, dev_b, pin_emb, node_type, buf0);
    k_count<<<(N_EDGES + 255) / 256, 256, 0, stream>>>(edge_idx, cnt);
    k_tail<<<(N_NODES + 255) / 256, 256, 0, stream>>>(y, out);

    const int gemm_grid = (N_NODES + BM - 1) / BM;
    float* xcur = buf0;
    float* xalt = buf1;
    for (int l = 0; l < NLAYERS; ++l) {
        hipMemsetAsync(xalt, 0, xelems * sizeof(float), stream);
        k_scatter<<<(N_EDGES * 64 + 255) / 256, 256, 0, stream>>>(xcur, edge_idx, xalt);
        k_layer<true><<<gemm_grid, 256, 0, stream>>>(
            xalt, xcur, cnt,
            sage_Wl + (size_t)l * HID * HID, sage_bl + (size_t)l * HID,
            sage_Wr + (size_t)l * HID * HID, xalt);
        float* t = xcur; xcur = xalt; xalt = t;
    }
    k_layer<false><<<gemm_grid, 256, 0, stream>>>(
        nullptr, xcur, nullptr, head_W0, head_b0, nullptr, xalt);
    k_pred<<<(N_NODES * 64 + 255) / 256, 256, 0, stream>>>(
        xalt, head_W1, head_b1, out);
}

// Round 2
// 698.766 us; speedup vs baseline: 6.8748x; 6.8748x over previous
//
#include <hip/hip_runtime.h>
#include <hip/hip_bf16.h>

#define N_NODES 100000
#define N_EDGES 320000
#define HID 256
#define NE 128
#define NLAYERS 3

typedef __attribute__((ext_vector_type(8))) short short8;
typedef __attribute__((ext_vector_type(4))) float f32x4;

__device__ inline float bfbits2f(unsigned int b) { return __uint_as_float(b << 16); }

// ---------------------------------------------------------------------------
// Weight prep: fp32 -> bf16, transposed to [n][k] so MFMA B-frags are
// contiguous bf16x8 loads.  Wt[l][n][k] = (k<256 ? Wl[l][k][n] : Wr[l][k-256][n])
// Wh[n][k] = W0[k][n]
// ---------------------------------------------------------------------------
__global__ __launch_bounds__(256) void k_prep(
    const float* __restrict__ Wl, const float* __restrict__ Wr,
    const float* __restrict__ W0,
    __hip_bfloat16* __restrict__ Wt, __hip_bfloat16* __restrict__ Wh)
{
    int t = blockIdx.x * 256 + threadIdx.x;
    const int total_sage = 3 * 256 * 512;
    if (t < total_sage) {
        int l = t >> 17;            // 131072 elems per layer
        int rem = t & 131071;
        int n = rem >> 9;
        int k = rem & 511;
        const float* Wsrc = (k < 256) ? (Wl + (size_t)l * 65536)
                                      : (Wr + (size_t)l * 65536);
        Wt[t] = __float2bfloat16(Wsrc[(k & 255) * 256 + n]);
    } else {
        int u = t - total_sage;
        if (u < 65536) {
            int n = u >> 8, k = u & 255;
            Wh[u] = __float2bfloat16(W0[k * 256 + n]);
        }
    }
}

// ---------------------------------------------------------------------------
// Init: x[n,0:128] = node_emb[type]; x[n,128:256] = per-type attr embedding
// ---------------------------------------------------------------------------
__global__ __launch_bounds__(256) void k_init(
    const float* __restrict__ node_attr,
    const float* __restrict__ node_emb,
    const float* __restrict__ net_W, const float* __restrict__ net_b,
    const float* __restrict__ dev_W, const float* __restrict__ dev_b,
    const float* __restrict__ pin_emb,
    const int*   __restrict__ node_type,
    __hip_bfloat16* __restrict__ x)
{
    int t = blockIdx.x * 256 + threadIdx.x;
    if (t >= N_NODES * NE) return;
    int n = t >> 7;
    int c = t & 127;
    int ty = node_type[n];
    float emb = node_emb[ty * NE + c];
    float a;
    if (ty == 0 || ty == 1) {
        const float* W = (ty == 0) ? net_W : dev_W;
        const float* b = (ty == 0) ? net_b : dev_b;
        float s = b[c];
        const float* ar = node_attr + (size_t)n * 17;
        #pragma unroll
        for (int k = 0; k < 17; ++k) s += ar[k] * W[k * NE + c];
        a = s;
    } else if (ty == 2) {
        int idx = (int)node_attr[(size_t)n * 17];
        a = pin_emb[idx * NE + c];
    } else {
        a = 0.0f;
    }
    x[(size_t)n * HID + c]      = __float2bfloat16(emb);
    x[(size_t)n * HID + NE + c] = __float2bfloat16(a);
}

// ---------------------------------------------------------------------------
// CSR build: histogram -> scan-free chunk allocation -> fill
// ---------------------------------------------------------------------------
__global__ __launch_bounds__(256) void k_hist(
    const int* __restrict__ edge_index, int* __restrict__ deg)
{
    int e = blockIdx.x * 256 + threadIdx.x;
    if (e < N_EDGES) atomicAdd(&deg[edge_index[N_EDGES + e]], 1);
}

__global__ __launch_bounds__(256) void k_alloc(
    const int* __restrict__ deg, int* __restrict__ off,
    int* __restrict__ cursor, int* __restrict__ total)
{
    int n = blockIdx.x * 256 + threadIdx.x;
    int lane = threadIdx.x & 63;
    int d = (n < N_NODES) ? deg[n] : 0;
    int incl = d;
    #pragma unroll
    for (int o = 1; o < 64; o <<= 1) {
        int v = __shfl_up(incl, o, 64);
        if (lane >= o) incl += v;
    }
    int wtot = __shfl(incl, 63, 64);
    int base = 0;
    if (lane == 63) base = atomicAdd(total, wtot);
    base = __shfl(base, 63, 64);
    if (n < N_NODES) {
        int o = base + incl - d;
        off[n] = o;
        cursor[n] = o;
    }
}

__global__ __launch_bounds__(256) void k_fill(
    const int* __restrict__ edge_index, int* __restrict__ cursor,
    int* __restrict__ slots)
{
    int e = blockIdx.x * 256 + threadIdx.x;
    if (e >= N_EDGES) return;
    int s = edge_index[e];
    int d = edge_index[N_EDGES + e];
    int slot = atomicAdd(&cursor[d], 1);
    slots[slot] = s;
}

// ---------------------------------------------------------------------------
// Gather-mean: one wave per node.  lane covers 4 cols (8B bf16).
// agg[n] = mean over neighbors of x[src]  (fp32 accumulate)
// ---------------------------------------------------------------------------
__global__ __launch_bounds__(256) void k_aggregate(
    const __hip_bfloat16* __restrict__ x,
    const int* __restrict__ off, const int* __restrict__ deg,
    const int* __restrict__ slots,
    __hip_bfloat16* __restrict__ agg)
{
    int g = blockIdx.x * 256 + threadIdx.x;
    int n = g >> 6;
    if (n >= N_NODES) return;
    int lane = g & 63;
    int o = off[n], d = deg[n];
    float s0 = 0, s1 = 0, s2 = 0, s3 = 0;
    for (int p = 0; p < d; ++p) {
        int src = slots[o + p];
        uint2 v = *reinterpret_cast<const uint2*>(x + (size_t)src * HID + lane * 4);
        s0 += bfbits2f(v.x & 0xffffu);
        s1 += __uint_as_float(v.x & 0xffff0000u);
        s2 += bfbits2f(v.y & 0xffffu);
        s3 += __uint_as_float(v.y & 0xffff0000u);
    }
    float rs = 1.0f / fmaxf((float)d, 1.0f);
    __hip_bfloat16 r0 = __float2bfloat16(s0 * rs);
    __hip_bfloat16 r1 = __float2bfloat16(s1 * rs);
    __hip_bfloat16 r2 = __float2bfloat16(s2 * rs);
    __hip_bfloat16 r3 = __float2bfloat16(s3 * rs);
    unsigned int lo = (unsigned int)*(unsigned short*)&r0 |
                      ((unsigned int)*(unsigned short*)&r1 << 16);
    unsigned int hi = (unsigned int)*(unsigned short*)&r2 |
                      ((unsigned int)*(unsigned short*)&r3 << 16);
    uint2 outv; outv.x = lo; outv.y = hi;
    *reinterpret_cast<uint2*>(agg + (size_t)n * HID + lane * 4) = outv;
}

// ---------------------------------------------------------------------------
// MFMA layer.  Block = 256 thr (4 waves) -> 64 rows; wave w -> cols w*64..+63.
// SAGE: out = relu([agg|x] @ Wt^T + bias)  (Wt is [256 n][512 k], bf16)
// HEAD: pred += relu(x @ Wh^T + bias) . W1  (atomicAdd partials, K=256)
// Fragment layout (verified m91/m92): a: lane holds row (l&15), k=8*(l>>4)+j;
// b: lane holds col (l&15) of B = row of Wt; d: col=l&15, row=4*(l>>4)+reg.
// ---------------------------------------------------------------------------
template <bool SAGE>
__global__ __launch_bounds__(256) void k_mfma(
    const __hip_bfloat16* __restrict__ Agg,
    const __hip_bfloat16* __restrict__ X,
    const __hip_bfloat16* __restrict__ Wt,
    const float* __restrict__ bias,
    const float* __restrict__ W1,
    __hip_bfloat16* __restrict__ Out,
    float* __restrict__ Pred)
{
    const int tid = threadIdx.x;
    const int w = tid >> 6, lane = tid & 63;
    const int l15 = lane & 15, lg = lane >> 4;
    const int row0 = blockIdx.x * 64;
    const int col0 = w * 64;
    const int KT = SAGE ? 512 : 256;

    f32x4 acc[4][4];
    #pragma unroll
    for (int i = 0; i < 4; ++i)
        #pragma unroll
        for (int n = 0; n < 4; ++n)
            acc[i][n] = (f32x4)0.0f;

    #pragma unroll
    for (int ks = 0; ks < (SAGE ? 16 : 8); ++ks) {
        const int k0 = ks * 32;
        const __hip_bfloat16* src;
        int kk;
        if (SAGE && ks < 8) { src = Agg; kk = k0; }
        else               { src = X;   kk = k0 & 255; }
        short8 a[4], b[4];
        #pragma unroll
        for (int i = 0; i < 4; ++i) {
            int r = row0 + i * 16 + l15;
            if (r >= N_NODES) r = N_NODES - 1;
            a[i] = *reinterpret_cast<const short8*>(src + (size_t)r * HID + kk + 8 * lg);
        }
        #pragma unroll
        for (int n = 0; n < 4; ++n) {
            int c = col0 + n * 16 + l15;
            b[n] = *reinterpret_cast<const short8*>(Wt + (size_t)c * KT + k0 + 8 * lg);
        }
        #pragma unroll
        for (int i = 0; i < 4; ++i)
            #pragma unroll
            for (int n = 0; n < 4; ++n)
                acc[i][n] = __builtin_amdgcn_mfma_f32_16x16x32_bf16(
                    a[i], b[n], acc[i][n], 0, 0, 0);
    }

    if (SAGE) {
        #pragma unroll
        for (int n = 0; n < 4; ++n) {
            int c = col0 + n * 16 + l15;
            float bv = bias[c];
            #pragma unroll
            for (int i = 0; i < 4; ++i) {
                #pragma unroll
                for (int r = 0; r < 4; ++r) {
                    int row = row0 + i * 16 + lg * 4 + r;
                    if (row < N_NODES)
                        Out[(size_t)row * HID + c] =
                            __float2bfloat16(fmaxf(acc[i][n][r] + bv, 0.0f));
                }
            }
        }
    } else {
        float p[4][4];
        #pragma unroll
        for (int i = 0; i < 4; ++i)
            #pragma unroll
            for (int r = 0; r < 4; ++r) p[i][r] = 0.0f;
        #pragma unroll
        for (int n = 0; n < 4; ++n) {
            int c = col0 + n * 16 + l15;
            float bv = bias[c];
            float wv = W1[c];
            #pragma unroll
            for (int i = 0; i < 4; ++i)
                #pragma unroll
                for (int r = 0; r < 4; ++r)
                    p[i][r] += fmaxf(acc[i][n][r] + bv, 0.0f) * wv;
        }
        #pragma unroll
        for (int i = 0; i < 4; ++i)
            #pragma unroll
            for (int r = 0; r < 4; ++r) {
                float s = p[i][r];
                #pragma unroll
                for (int m = 1; m < 16; m <<= 1) s += __shfl_xor(s, m, 64);
                if (l15 == 0) {
                    int row = row0 + i * 16 + lg * 4 + r;
                    if (row < N_NODES) atomicAdd(&Pred[row], s);
                }
            }
    }
}

// ---------------------------------------------------------------------------
// Tail: pred init = b1; true_class = trunc(y[:,1]); true_label = y
// ---------------------------------------------------------------------------
__global__ __launch_bounds__(256) void k_tail(
    const float* __restrict__ y, const float* __restrict__ b1,
    float* __restrict__ out)
{
    int i = blockIdx.x * 256 + threadIdx.x;
    if (i >= N_NODES) return;
    float y0 = y[(size_t)i * 2 + 0];
    float y1 = y[(size_t)i * 2 + 1];
    out[i] = b1[0];
    out[N_NODES + i] = (float)(int)y1;
    out[2 * N_NODES + 2 * i + 0] = y0;
    out[2 * N_NODES + 2 * i + 1] = y1;
}

extern "C" void kernel_launch(void* const* d_in, const int* in_sizes, int n_in,
                              void* d_out, int out_size, void* d_ws, size_t ws_size,
                              hipStream_t stream) {
    const float* node_attr = (const float*)d_in[0];
    const float* y         = (const float*)d_in[1];
    const float* node_emb  = (const float*)d_in[2];
    const float* net_W     = (const float*)d_in[4];
    const float* net_b     = (const float*)d_in[5];
    const float* dev_W     = (const float*)d_in[6];
    const float* dev_b     = (const float*)d_in[7];
    const float* pin_emb   = (const float*)d_in[8];
    const float* sage_Wl   = (const float*)d_in[9];
    const float* sage_bl   = (const float*)d_in[10];
    const float* sage_Wr   = (const float*)d_in[11];
    const float* head_W0   = (const float*)d_in[12];
    const float* head_b0   = (const float*)d_in[13];
    const float* head_W1   = (const float*)d_in[14];
    const float* head_b1   = (const float*)d_in[15];
    const int*   node_type = (const int*)d_in[16];
    const int*   edge_idx  = (const int*)d_in[18];
    float* out = (float*)d_out;

    // workspace carve-up (bf16 elems unless noted)
    const size_t xelems = (size_t)N_NODES * HID;          // 25.6M elems
    char* p = (char*)d_ws;
    __hip_bfloat16* x0  = (__hip_bfloat16*)p;  p += xelems * 2;
    __hip_bfloat16* x1  = (__hip_bfloat16*)p;  p += xelems * 2;
    __hip_bfloat16* agg = (__hip_bfloat16*)p;  p += xelems * 2;
    __hip_bfloat16* Wt  = (__hip_bfloat16*)p;  p += (size_t)3 * 256 * 512 * 2;
    __hip_bfloat16* Wh  = (__hip_bfloat16*)p;  p += (size_t)256 * 256 * 2;
    int* deg    = (int*)p; p += N_NODES * 4;
    int* off    = (int*)p; p += N_NODES * 4;
    int* cursor = (int*)p; p += N_NODES * 4;
    int* slots  = (int*)p; p += N_EDGES * 4;
    int* total  = (int*)p; p += 16;

    hipMemsetAsync(deg, 0, N_NODES * sizeof(int), stream);
    hipMemsetAsync(total, 0, sizeof(int), stream);

    k_prep<<<(3 * 131072 + 65536 + 255) / 256, 256, 0, stream>>>(
        sage_Wl, sage_Wr, head_W0, Wt, Wh);
    k_init<<<(N_NODES * NE + 255) / 256, 256, 0, stream>>>(
        node_attr, node_emb, net_W, net_b, dev_W, dev_b, pin_emb, node_type, x0);
    k_tail<<<(N_NODES + 255) / 256, 256, 0, stream>>>(y, head_b1, out);
    k_hist<<<(N_EDGES + 255) / 256, 256, 0, stream>>>(edge_idx, deg);
    k_alloc<<<(N_NODES + 255) / 256, 256, 0, stream>>>(deg, off, cursor, total);
    k_fill<<<(N_EDGES + 255) / 256, 256, 0, stream>>>(edge_idx, cursor, slots);

    const int gemm_grid = (N_NODES + 63) / 64;
    __hip_bfloat16* xcur = x0;
    __hip_bfloat16* xalt = x1;
    for (int l = 0; l < NLAYERS; ++l) {
        k_aggregate<<<(N_NODES * 64 + 255) / 256, 256, 0, stream>>>(
            xcur, off, deg, slots, agg);
        k_mfma<true><<<gemm_grid, 256, 0, stream>>>(
            agg, xcur, Wt + (size_t)l * 131072,
            sage_bl + (size_t)l * HID, nullptr, xalt, nullptr);
        __hip_bfloat16* t = xcur; xcur = xalt; xalt = t;
    }
    k_mfma<false><<<gemm_grid, 256, 0, stream>>>(
        xcur, xcur, Wh, head_b0, head_W1, nullptr, out);
}

// Round 3
// 579.369 us; speedup vs baseline: 8.2915x; 1.2061x over previous
//
#include <hip/hip_runtime.h>
#include <hip/hip_bf16.h>

#define N_NODES 100000
#define N_EDGES 320000
#define HID 256
#define NE 128
#define NLAYERS 3

typedef __attribute__((ext_vector_type(8))) short short8;
typedef __attribute__((ext_vector_type(4))) float f32x4;

__device__ inline float bfbits2f(unsigned int b) { return __uint_as_float(b << 16); }

// ---------------------------------------------------------------------------
// Weight prep: fp32 -> bf16, transposed to [n][k].
// Wt[l][n][k] = (k<256 ? Wl[l][k][n] : Wr[l][k-256][n]);  Wh[n][k] = W0[k][n]
// ---------------------------------------------------------------------------
__global__ __launch_bounds__(256) void k_prep(
    const float* __restrict__ Wl, const float* __restrict__ Wr,
    const float* __restrict__ W0,
    __hip_bfloat16* __restrict__ Wt, __hip_bfloat16* __restrict__ Wh)
{
    int t = blockIdx.x * 256 + threadIdx.x;
    const int total_sage = 3 * 256 * 512;
    if (t < total_sage) {
        int l = t >> 17;
        int rem = t & 131071;
        int n = rem >> 9;
        int k = rem & 511;
        const float* Wsrc = (k < 256) ? (Wl + (size_t)l * 65536)
                                      : (Wr + (size_t)l * 65536);
        Wt[t] = __float2bfloat16(Wsrc[(k & 255) * 256 + n]);
    } else {
        int u = t - total_sage;
        if (u < 65536) {
            int n = u >> 8, k = u & 255;
            Wh[u] = __float2bfloat16(W0[k * 256 + n]);
        }
    }
}

// ---------------------------------------------------------------------------
// Init: x[n,0:128] = node_emb[type]; x[n,128:256] = per-type attr embedding
// ---------------------------------------------------------------------------
__global__ __launch_bounds__(256) void k_init(
    const float* __restrict__ node_attr,
    const float* __restrict__ node_emb,
    const float* __restrict__ net_W, const float* __restrict__ net_b,
    const float* __restrict__ dev_W, const float* __restrict__ dev_b,
    const float* __restrict__ pin_emb,
    const int*   __restrict__ node_type,
    __hip_bfloat16* __restrict__ x)
{
    int t = blockIdx.x * 256 + threadIdx.x;
    if (t >= N_NODES * NE) return;
    int n = t >> 7;
    int c = t & 127;
    int ty = node_type[n];
    float emb = node_emb[ty * NE + c];
    float a;
    if (ty == 0 || ty == 1) {
        const float* W = (ty == 0) ? net_W : dev_W;
        const float* b = (ty == 0) ? net_b : dev_b;
        float s = b[c];
        const float* ar = node_attr + (size_t)n * 17;
        #pragma unroll
        for (int k = 0; k < 17; ++k) s += ar[k] * W[k * NE + c];
        a = s;
    } else if (ty == 2) {
        int idx = (int)node_attr[(size_t)n * 17];
        a = pin_emb[idx * NE + c];
    } else {
        a = 0.0f;
    }
    x[(size_t)n * HID + c]      = __float2bfloat16(emb);
    x[(size_t)n * HID + NE + c] = __float2bfloat16(a);
}

// ---------------------------------------------------------------------------
// CSR build: histogram -> scan-free chunk allocation -> fill
// ---------------------------------------------------------------------------
__global__ __launch_bounds__(256) void k_hist(
    const int* __restrict__ edge_index, int* __restrict__ deg)
{
    int e = blockIdx.x * 256 + threadIdx.x;
    if (e < N_EDGES) atomicAdd(&deg[edge_index[N_EDGES + e]], 1);
}

__global__ __launch_bounds__(256) void k_alloc(
    const int* __restrict__ deg, int* __restrict__ off,
    int* __restrict__ cursor, int* __restrict__ total)
{
    int n = blockIdx.x * 256 + threadIdx.x;
    int lane = threadIdx.x & 63;
    int d = (n < N_NODES) ? deg[n] : 0;
    int incl = d;
    #pragma unroll
    for (int o = 1; o < 64; o <<= 1) {
        int v = __shfl_up(incl, o, 64);
        if (lane >= o) incl += v;
    }
    int wtot = __shfl(incl, 63, 64);
    int base = 0;
    if (lane == 63) base = atomicAdd(total, wtot);
    base = __shfl(base, 63, 64);
    if (n < N_NODES) {
        int o = base + incl - d;
        off[n] = o;
        cursor[n] = o;
    }
}

__global__ __launch_bounds__(256) void k_fill(
    const int* __restrict__ edge_index, int* __restrict__ cursor,
    int* __restrict__ slots)
{
    int e = blockIdx.x * 256 + threadIdx.x;
    if (e >= N_EDGES) return;
    int s = edge_index[e];
    int d = edge_index[N_EDGES + e];
    int slot = atomicAdd(&cursor[d], 1);
    slots[slot] = s;
}

// ---------------------------------------------------------------------------
// Gather-mean: one wave per node, lane covers 4 cols (8B), fp32 accumulate.
// ---------------------------------------------------------------------------
__global__ __launch_bounds__(256) void k_aggregate(
    const __hip_bfloat16* __restrict__ x,
    const int* __restrict__ off, const int* __restrict__ deg,
    const int* __restrict__ slots,
    __hip_bfloat16* __restrict__ agg)
{
    int g = blockIdx.x * 256 + threadIdx.x;
    int n = g >> 6;
    if (n >= N_NODES) return;
    int lane = g & 63;
    int o = off[n], d = deg[n];
    float s0 = 0, s1 = 0, s2 = 0, s3 = 0;
    for (int p = 0; p < d; ++p) {
        int src = slots[o + p];
        uint2 v = *reinterpret_cast<const uint2*>(x + (size_t)src * HID + lane * 4);
        s0 += bfbits2f(v.x & 0xffffu);
        s1 += __uint_as_float(v.x & 0xffff0000u);
        s2 += bfbits2f(v.y & 0xffffu);
        s3 += __uint_as_float(v.y & 0xffff0000u);
    }
    float rs = 1.0f / fmaxf((float)d, 1.0f);
    __hip_bfloat16 r0 = __float2bfloat16(s0 * rs);
    __hip_bfloat16 r1 = __float2bfloat16(s1 * rs);
    __hip_bfloat16 r2 = __float2bfloat16(s2 * rs);
    __hip_bfloat16 r3 = __float2bfloat16(s3 * rs);
    unsigned int lo = (unsigned int)*(unsigned short*)&r0 |
                      ((unsigned int)*(unsigned short*)&r1 << 16);
    unsigned int hi = (unsigned int)*(unsigned short*)&r2 |
                      ((unsigned int)*(unsigned short*)&r3 << 16);
    uint2 outv; outv.x = lo; outv.y = hi;
    *reinterpret_cast<uint2*>(agg + (size_t)n * HID + lane * 4) = outv;
}

// ---------------------------------------------------------------------------
// MFMA layer, m97-style structure scaled down.
// Block = 512 thr (8 waves, 2 row x 4 col wave grid); tile 128 rows x 256 cols.
// A (node rows) staged in LDS via global_load_lds w16, double-buffered BK=64,
// XOR-swizzled (pre-swizzled global source, linear LDS dest, swizzled ds_read).
// B (weights, [n][k] bf16) read direct from global (L2-resident).
// SAGE: Out = relu([Agg|X] @ Wt^T + bias)   (K=512)
// HEAD: Pred += relu(X @ Wh^T + bias) . W1  (K=256, atomicAdd partials)
// ---------------------------------------------------------------------------
template <bool SAGE>
__global__ __launch_bounds__(512) void k_mfma(
    const __hip_bfloat16* __restrict__ Agg,
    const __hip_bfloat16* __restrict__ X,
    const __hip_bfloat16* __restrict__ Wt,
    const float* __restrict__ bias,
    const float* __restrict__ W1,
    __hip_bfloat16* __restrict__ Out,
    float* __restrict__ Pred)
{
    __shared__ char As[2][16384];   // 2 x (128 rows x 64 k x bf16)

    const int tid  = threadIdx.x;
    const int w    = tid >> 6, lane = tid & 63;
    const int wr   = w >> 2,  wc   = w & 3;
    const int l15  = lane & 15, lg = lane >> 4;
    const int row0 = blockIdx.x * 128;
    const int KT     = SAGE ? 512 : 256;
    const int nsteps = SAGE ? 8 : 4;

    f32x4 acc[4][4];
    #pragma unroll
    for (int i = 0; i < 4; ++i)
        #pragma unroll
        for (int n = 0; n < 4; ++n) acc[i][n] = (f32x4)0.0f;

    const int srow   = w * 8 + (lane >> 3);  // local row covered by this thread
    const int schunk = lane & 7;             // 16B chunk within the 128B row

    auto stage = [&](int s, int b) {
        const char* base;
        int k0;
        if (SAGE && s < 4) { base = (const char*)Agg; k0 = s * 64; }
        else               { base = (const char*)X;   k0 = (SAGE ? s - 4 : s) * 64; }
        #pragma unroll
        for (int issue = 0; issue < 2; ++issue) {
            int row  = srow + issue * 64;
            int grow = row0 + row;
            if (grow >= N_NODES) grow = N_NODES - 1;
            const char* gp = base + (size_t)grow * 512 + (size_t)k0 * 2
                           + ((schunk ^ (row & 7)) << 4);   // inverse swizzle on src
            const char* lp = &As[b][issue * 8192 + w * 1024 + lane * 16]; // linear dest
            __builtin_amdgcn_global_load_lds(
                (const __attribute__((address_space(1))) void*)gp,
                (__attribute__((address_space(3))) void*)lp, 16, 0, 0);
        }
    };

    stage(0, 0);
    __syncthreads();
    for (int s = 0; s < nsteps; ++s) {
        const int b = s & 1;
        if (s + 1 < nsteps) stage(s + 1, b ^ 1);
        const int k0w = s * 64;
        #pragma unroll
        for (int h = 0; h < 2; ++h) {
            short8 a[4], bb[4];
            #pragma unroll
            for (int i = 0; i < 4; ++i) {
                int r = wr * 64 + i * 16 + l15;
                a[i] = *(const short8*)&As[b][r * 128 + (((lg + 4 * h) ^ (r & 7)) << 4)];
            }
            #pragma unroll
            for (int n = 0; n < 4; ++n) {
                int c = wc * 64 + n * 16 + l15;
                bb[n] = *(const short8*)(Wt + (size_t)c * KT + k0w + h * 32 + 8 * lg);
            }
            #pragma unroll
            for (int i = 0; i < 4; ++i)
                #pragma unroll
                for (int n = 0; n < 4; ++n)
                    acc[i][n] = __builtin_amdgcn_mfma_f32_16x16x32_bf16(
                        a[i], bb[n], acc[i][n], 0, 0, 0);
        }
        __syncthreads();   // drains vmcnt (staged loads) + protects dbuf swap
    }

    if (SAGE) {
        // Epilogue via LDS for coalesced 16B stores (reuse As = 32KB = 64x256 bf16)
        __hip_bfloat16* lo = (__hip_bfloat16*)As;
        #pragma unroll
        for (int h = 0; h < 2; ++h) {
            if (wr == h) {
                #pragma unroll
                for (int n = 0; n < 4; ++n) {
                    int c = wc * 64 + n * 16 + l15;
                    float bv = bias[c];
                    #pragma unroll
                    for (int i = 0; i < 4; ++i)
                        #pragma unroll
                        for (int r = 0; r < 4; ++r) {
                            int rl = i * 16 + lg * 4 + r;
                            lo[rl * 256 + c] =
                                __float2bfloat16(fmaxf(acc[i][n][r] + bv, 0.0f));
                        }
                }
            }
            __syncthreads();
            #pragma unroll
            for (int q = 0; q < 4; ++q) {
                int chunk = tid + q * 512;        // 2048 x 16B = 64 rows x 512B
                int rl = chunk >> 5, cc = chunk & 31;
                int grow = row0 + h * 64 + rl;
                if (grow < N_NODES)
                    *(uint4*)((char*)Out + (size_t)grow * 512 + cc * 16) =
                        *(const uint4*)((const char*)As + rl * 512 + cc * 16);
            }
            __syncthreads();
        }
    } else {
        float p[4][4];
        #pragma unroll
        for (int i = 0; i < 4; ++i)
            #pragma unroll
            for (int r = 0; r < 4; ++r) p[i][r] = 0.0f;
        #pragma unroll
        for (int n = 0; n < 4; ++n) {
            int c = wc * 64 + n * 16 + l15;
            float bv = bias[c];
            float wv = W1[c];
            #pragma unroll
            for (int i = 0; i < 4; ++i)
                #pragma unroll
                for (int r = 0; r < 4; ++r)
                    p[i][r] += fmaxf(acc[i][n][r] + bv, 0.0f) * wv;
        }
        #pragma unroll
        for (int i = 0; i < 4; ++i)
            #pragma unroll
            for (int r = 0; r < 4; ++r) {
                float s = p[i][r];
                #pragma unroll
                for (int m = 1; m < 16; m <<= 1) s += __shfl_xor(s, m, 64);
                if (l15 == 0) {
                    int row = row0 + wr * 64 + i * 16 + lg * 4 + r;
                    if (row < N_NODES) atomicAdd(&Pred[row], s);
                }
            }
    }
}

// ---------------------------------------------------------------------------
// Tail: pred init = b1; true_class = trunc(y[:,1]); true_label = y
// ---------------------------------------------------------------------------
__global__ __launch_bounds__(256) void k_tail(
    const float* __restrict__ y, const float* __restrict__ b1,
    float* __restrict__ out)
{
    int i = blockIdx.x * 256 + threadIdx.x;
    if (i >= N_NODES) return;
    float y0 = y[(size_t)i * 2 + 0];
    float y1 = y[(size_t)i * 2 + 1];
    out[i] = b1[0];
    out[N_NODES + i] = (float)(int)y1;
    out[2 * N_NODES + 2 * i + 0] = y0;
    out[2 * N_NODES + 2 * i + 1] = y1;
}

extern "C" void kernel_launch(void* const* d_in, const int* in_sizes, int n_in,
                              void* d_out, int out_size, void* d_ws, size_t ws_size,
                              hipStream_t stream) {
    const float* node_attr = (const float*)d_in[0];
    const float* y         = (const float*)d_in[1];
    const float* node_emb  = (const float*)d_in[2];
    const float* net_W     = (const float*)d_in[4];
    const float* net_b     = (const float*)d_in[5];
    const float* dev_W     = (const float*)d_in[6];
    const float* dev_b     = (const float*)d_in[7];
    const float* pin_emb   = (const float*)d_in[8];
    const float* sage_Wl   = (const float*)d_in[9];
    const float* sage_bl   = (const float*)d_in[10];
    const float* sage_Wr   = (const float*)d_in[11];
    const float* head_W0   = (const float*)d_in[12];
    const float* head_b0   = (const float*)d_in[13];
    const float* head_W1   = (const float*)d_in[14];
    const float* head_b1   = (const float*)d_in[15];
    const int*   node_type = (const int*)d_in[16];
    const int*   edge_idx  = (const int*)d_in[18];
    float* out = (float*)d_out;

    const size_t xelems = (size_t)N_NODES * HID;
    char* p = (char*)d_ws;
    __hip_bfloat16* x0  = (__hip_bfloat16*)p;  p += xelems * 2;
    __hip_bfloat16* x1  = (__hip_bfloat16*)p;  p += xelems * 2;
    __hip_bfloat16* agg = (__hip_bfloat16*)p;  p += xelems * 2;
    __hip_bfloat16* Wt  = (__hip_bfloat16*)p;  p += (size_t)3 * 256 * 512 * 2;
    __hip_bfloat16* Wh  = (__hip_bfloat16*)p;  p += (size_t)256 * 256 * 2;
    int* deg    = (int*)p; p += N_NODES * 4;
    int* off    = (int*)p; p += N_NODES * 4;
    int* cursor = (int*)p; p += N_NODES * 4;
    int* slots  = (int*)p; p += N_EDGES * 4;
    int* total  = (int*)p; p += 16;

    hipMemsetAsync(deg, 0, N_NODES * sizeof(int), stream);
    hipMemsetAsync(total, 0, sizeof(int), stream);

    k_prep<<<(3 * 131072 + 65536 + 255) / 256, 256, 0, stream>>>(
        sage_Wl, sage_Wr, head_W0, Wt, Wh);
    k_init<<<(N_NODES * NE + 255) / 256, 256, 0, stream>>>(
        node_attr, node_emb, net_W, net_b, dev_W, dev_b, pin_emb, node_type, x0);
    k_tail<<<(N_NODES + 255) / 256, 256, 0, stream>>>(y, head_b1, out);
    k_hist<<<(N_EDGES + 255) / 256, 256, 0, stream>>>(edge_idx, deg);
    k_alloc<<<(N_NODES + 255) / 256, 256, 0, stream>>>(deg, off, cursor, total);
    k_fill<<<(N_EDGES + 255) / 256, 256, 0, stream>>>(edge_idx, cursor, slots);

    const int gemm_grid = (N_NODES + 127) / 128;
    __hip_bfloat16* xcur = x0;
    __hip_bfloat16* xalt = x1;
    for (int l = 0; l < NLAYERS; ++l) {
        k_aggregate<<<(N_NODES * 64 + 255) / 256, 256, 0, stream>>>(
            xcur, off, deg, slots, agg);
        k_mfma<true><<<gemm_grid, 512, 0, stream>>>(
            agg, xcur, Wt + (size_t)l * 131072,
            sage_bl + (size_t)l * HID, nullptr, xalt, nullptr);
        __hip_bfloat16* t = xcur; xcur = xalt; xalt = t;
    }
    k_mfma<false><<<gemm_grid, 512, 0, stream>>>(
        xcur, xcur, Wh, head_b0, head_W1, nullptr, out);
}

// Round 4
// 526.996 us; speedup vs baseline: 9.1155x; 1.0994x over previous
//
#include <hip/hip_runtime.h>
#include <hip/hip_bf16.h>

#define N_NODES 100000
#define N_EDGES 320000
#define HID 256
#define NE 128
#define NLAYERS 3

typedef __attribute__((ext_vector_type(8))) short short8;
typedef __attribute__((ext_vector_type(4))) float f32x4;

__device__ inline float bfbits2f(unsigned int b) { return __uint_as_float(b << 16); }

// ---------------------------------------------------------------------------
// Weight prep: fp32 -> bf16, transposed to [n][k].
// Wt[l][n][k] = (k<256 ? Wl[l][k][n] : Wr[l][k-256][n]);  Wh[n][k] = W0[k][n]
// ---------------------------------------------------------------------------
__global__ __launch_bounds__(256) void k_prep(
    const float* __restrict__ Wl, const float* __restrict__ Wr,
    const float* __restrict__ W0,
    __hip_bfloat16* __restrict__ Wt, __hip_bfloat16* __restrict__ Wh)
{
    int t = blockIdx.x * 256 + threadIdx.x;
    const int total_sage = 3 * 256 * 512;
    if (t < total_sage) {
        int l = t >> 17;
        int rem = t & 131071;
        int n = rem >> 9;
        int k = rem & 511;
        const float* Wsrc = (k < 256) ? (Wl + (size_t)l * 65536)
                                      : (Wr + (size_t)l * 65536);
        Wt[t] = __float2bfloat16(Wsrc[(k & 255) * 256 + n]);
    } else {
        int u = t - total_sage;
        if (u < 65536) {
            int n = u >> 8, k = u & 255;
            Wh[u] = __float2bfloat16(W0[k * 256 + n]);
        }
    }
}

// ---------------------------------------------------------------------------
// Init: x[n,0:128] = node_emb[type]; x[n,128:256] = per-type attr embedding
// ---------------------------------------------------------------------------
__global__ __launch_bounds__(256) void k_init(
    const float* __restrict__ node_attr,
    const float* __restrict__ node_emb,
    const float* __restrict__ net_W, const float* __restrict__ net_b,
    const float* __restrict__ dev_W, const float* __restrict__ dev_b,
    const float* __restrict__ pin_emb,
    const int*   __restrict__ node_type,
    __hip_bfloat16* __restrict__ x)
{
    int t = blockIdx.x * 256 + threadIdx.x;
    if (t >= N_NODES * NE) return;
    int n = t >> 7;
    int c = t & 127;
    int ty = node_type[n];
    float emb = node_emb[ty * NE + c];
    float a;
    if (ty == 0 || ty == 1) {
        const float* W = (ty == 0) ? net_W : dev_W;
        const float* b = (ty == 0) ? net_b : dev_b;
        float s = b[c];
        const float* ar = node_attr + (size_t)n * 17;
        #pragma unroll
        for (int k = 0; k < 17; ++k) s += ar[k] * W[k * NE + c];
        a = s;
    } else if (ty == 2) {
        int idx = (int)node_attr[(size_t)n * 17];
        a = pin_emb[idx * NE + c];
    } else {
        a = 0.0f;
    }
    x[(size_t)n * HID + c]      = __float2bfloat16(emb);
    x[(size_t)n * HID + NE + c] = __float2bfloat16(a);
}

// ---------------------------------------------------------------------------
// CSR build: histogram -> scan-free chunk allocation -> fill
// ---------------------------------------------------------------------------
__global__ __launch_bounds__(256) void k_hist(
    const int* __restrict__ edge_index, int* __restrict__ deg)
{
    int e = blockIdx.x * 256 + threadIdx.x;
    if (e < N_EDGES) atomicAdd(&deg[edge_index[N_EDGES + e]], 1);
}

__global__ __launch_bounds__(256) void k_alloc(
    const int* __restrict__ deg, int* __restrict__ off,
    int* __restrict__ cursor, int* __restrict__ total)
{
    int n = blockIdx.x * 256 + threadIdx.x;
    int lane = threadIdx.x & 63;
    int d = (n < N_NODES) ? deg[n] : 0;
    int incl = d;
    #pragma unroll
    for (int o = 1; o < 64; o <<= 1) {
        int v = __shfl_up(incl, o, 64);
        if (lane >= o) incl += v;
    }
    int wtot = __shfl(incl, 63, 64);
    int base = 0;
    if (lane == 63) base = atomicAdd(total, wtot);
    base = __shfl(base, 63, 64);
    if (n < N_NODES) {
        int o = base + incl - d;
        off[n] = o;
        cursor[n] = o;
    }
}

__global__ __launch_bounds__(256) void k_fill(
    const int* __restrict__ edge_index, int* __restrict__ cursor,
    int* __restrict__ slots)
{
    int e = blockIdx.x * 256 + threadIdx.x;
    if (e >= N_EDGES) return;
    int s = edge_index[e];
    int d = edge_index[N_EDGES + e];
    int slot = atomicAdd(&cursor[d], 1);
    slots[slot] = s;
}

// ---------------------------------------------------------------------------
// Gather-mean: one wave per node, lane covers 4 cols (8B), fp32 accumulate.
// ---------------------------------------------------------------------------
__global__ __launch_bounds__(256) void k_aggregate(
    const __hip_bfloat16* __restrict__ x,
    const int* __restrict__ off, const int* __restrict__ deg,
    const int* __restrict__ slots,
    __hip_bfloat16* __restrict__ agg)
{
    int g = blockIdx.x * 256 + threadIdx.x;
    int n = g >> 6;
    if (n >= N_NODES) return;
    int lane = g & 63;
    int o = off[n], d = deg[n];
    float s0 = 0, s1 = 0, s2 = 0, s3 = 0;
    for (int p = 0; p < d; ++p) {
        int src = slots[o + p];
        uint2 v = *reinterpret_cast<const uint2*>(x + (size_t)src * HID + lane * 4);
        s0 += bfbits2f(v.x & 0xffffu);
        s1 += __uint_as_float(v.x & 0xffff0000u);
        s2 += bfbits2f(v.y & 0xffffu);
        s3 += __uint_as_float(v.y & 0xffff0000u);
    }
    float rs = 1.0f / fmaxf((float)d, 1.0f);
    __hip_bfloat16 r0 = __float2bfloat16(s0 * rs);
    __hip_bfloat16 r1 = __float2bfloat16(s1 * rs);
    __hip_bfloat16 r2 = __float2bfloat16(s2 * rs);
    __hip_bfloat16 r3 = __float2bfloat16(s3 * rs);
    unsigned int lo = (unsigned int)*(unsigned short*)&r0 |
                      ((unsigned int)*(unsigned short*)&r1 << 16);
    unsigned int hi = (unsigned int)*(unsigned short*)&r2 |
                      ((unsigned int)*(unsigned short*)&r3 << 16);
    uint2 outv; outv.x = lo; outv.y = hi;
    *reinterpret_cast<uint2*>(agg + (size_t)n * HID + lane * 4) = outv;
}

// ---------------------------------------------------------------------------
// MFMA layer with 2-deep counted-vmcnt pipeline (T3/T4).
// Block = 512 thr (8 waves, 2x4); tile 128 rows x 256 cols; BK=64 dbuf.
// A staged via global_load_lds w16 (XOR-swizzled source, linear LDS dest,
// swizzled ds_read).  stage(s+2) issued after the read-done barrier; loop
// head waits s_waitcnt vmcnt(2) (stage(s) landed, stage(s+2) in flight) —
// no vmcnt(0) drain anywhere in the main loop.
// SAGE: Out = relu([Agg|X] @ Wt^T + bias)   (K=512)
// HEAD: Pred += relu(X @ Wh^T + bias) . W1  (K=256, atomicAdd partials)
// ---------------------------------------------------------------------------
template <bool SAGE>
__global__ __launch_bounds__(512) void k_mfma(
    const __hip_bfloat16* __restrict__ Agg,
    const __hip_bfloat16* __restrict__ X,
    const __hip_bfloat16* __restrict__ Wt,
    const float* __restrict__ bias,
    const float* __restrict__ W1,
    __hip_bfloat16* __restrict__ Out,
    float* __restrict__ Pred)
{
    __shared__ char As[2][16384];   // 2 x (128 rows x 64 k x bf16)

    const int tid  = threadIdx.x;
    const int w    = tid >> 6, lane = tid & 63;
    const int wr   = w >> 2,  wc   = w & 3;
    const int l15  = lane & 15, lg = lane >> 4;
    const int row0 = blockIdx.x * 128;
    const int KT     = SAGE ? 512 : 256;
    const int nsteps = SAGE ? 8 : 4;

    f32x4 acc[4][4];
    #pragma unroll
    for (int i = 0; i < 4; ++i)
        #pragma unroll
        for (int n = 0; n < 4; ++n) acc[i][n] = (f32x4)0.0f;

    const int srow   = w * 8 + (lane >> 3);  // local row covered by this thread
    const int schunk = lane & 7;             // 16B chunk within the 128B row

    auto stage = [&](int s, int b) {
        const char* base;
        int k0;
        if (SAGE && s < 4) { base = (const char*)Agg; k0 = s * 64; }
        else               { base = (const char*)X;   k0 = (SAGE ? s - 4 : s) * 64; }
        #pragma unroll
        for (int issue = 0; issue < 2; ++issue) {
            int row  = srow + issue * 64;
            int grow = row0 + row;
            if (grow >= N_NODES) grow = N_NODES - 1;
            const char* gp = base + (size_t)grow * 512 + (size_t)k0 * 2
                           + ((schunk ^ (row & 7)) << 4);   // inverse swizzle on src
            const char* lp = &As[b][issue * 8192 + w * 1024 + lane * 16]; // linear dest
            __builtin_amdgcn_global_load_lds(
                (const __attribute__((address_space(1))) void*)gp,
                (__attribute__((address_space(3))) void*)lp, 16, 0, 0);
        }
    };

    stage(0, 0);
    stage(1, 1);
    for (int s = 0; s < nsteps; ++s) {
        const int b = s & 1;
        // stage(s) landed when at most the 2 newest (stage s+2 / s+1) remain.
        asm volatile("s_waitcnt vmcnt(2)" ::: "memory");
        __builtin_amdgcn_sched_barrier(0);
        __builtin_amdgcn_s_barrier();
        __builtin_amdgcn_sched_barrier(0);
        const int k0w = s * 64;
        #pragma unroll
        for (int h = 0; h < 2; ++h) {
            short8 a[4], bb[4];
            #pragma unroll
            for (int i = 0; i < 4; ++i) {
                int r = wr * 64 + i * 16 + l15;
                a[i] = *(const short8*)&As[b][r * 128 + (((lg + 4 * h) ^ (r & 7)) << 4)];
            }
            #pragma unroll
            for (int n = 0; n < 4; ++n) {
                int c = wc * 64 + n * 16 + l15;
                bb[n] = *(const short8*)(Wt + (size_t)c * KT + k0w + h * 32 + 8 * lg);
            }
            #pragma unroll
            for (int i = 0; i < 4; ++i)
                #pragma unroll
                for (int n = 0; n < 4; ++n)
                    acc[i][n] = __builtin_amdgcn_mfma_f32_16x16x32_bf16(
                        a[i], bb[n], acc[i][n], 0, 0, 0);
        }
        __builtin_amdgcn_sched_barrier(0);
        __builtin_amdgcn_s_barrier();   // all waves done reading As[b]
        __builtin_amdgcn_sched_barrier(0);
        if (s + 2 < nsteps) stage(s + 2, b);
    }

    if (SAGE) {
        // Epilogue via LDS for coalesced 16B stores (reuse As = 32KB = 64x256 bf16)
        __hip_bfloat16* lo = (__hip_bfloat16*)As;
        #pragma unroll
        for (int h = 0; h < 2; ++h) {
            if (wr == h) {
                #pragma unroll
                for (int n = 0; n < 4; ++n) {
                    int c = wc * 64 + n * 16 + l15;
                    float bv = bias[c];
                    #pragma unroll
                    for (int i = 0; i < 4; ++i)
                        #pragma unroll
                        for (int r = 0; r < 4; ++r) {
                            int rl = i * 16 + lg * 4 + r;
                            lo[rl * 256 + c] =
                                __float2bfloat16(fmaxf(acc[i][n][r] + bv, 0.0f));
                        }
                }
            }
            __syncthreads();
            #pragma unroll
            for (int q = 0; q < 4; ++q) {
                int chunk = tid + q * 512;        // 2048 x 16B = 64 rows x 512B
                int rl = chunk >> 5, cc = chunk & 31;
                int grow = row0 + h * 64 + rl;
                if (grow < N_NODES)
                    *(uint4*)((char*)Out + (size_t)grow * 512 + cc * 16) =
                        *(const uint4*)((const char*)As + rl * 512 + cc * 16);
            }
            __syncthreads();
        }
    } else {
        float p[4][4];
        #pragma unroll
        for (int i = 0; i < 4; ++i)
            #pragma unroll
            for (int r = 0; r < 4; ++r) p[i][r] = 0.0f;
        #pragma unroll
        for (int n = 0; n < 4; ++n) {
            int c = wc * 64 + n * 16 + l15;
            float bv = bias[c];
            float wv = W1[c];
            #pragma unroll
            for (int i = 0; i < 4; ++i)
                #pragma unroll
                for (int r = 0; r < 4; ++r)
                    p[i][r] += fmaxf(acc[i][n][r] + bv, 0.0f) * wv;
        }
        #pragma unroll
        for (int i = 0; i < 4; ++i)
            #pragma unroll
            for (int r = 0; r < 4; ++r) {
                float s = p[i][r];
                #pragma unroll
                for (int m = 1; m < 16; m <<= 1) s += __shfl_xor(s, m, 64);
                if (l15 == 0) {
                    int row = row0 + wr * 64 + i * 16 + lg * 4 + r;
                    if (row < N_NODES) atomicAdd(&Pred[row], s);
                }
            }
    }
}

// ---------------------------------------------------------------------------
// Tail: pred init = b1; true_class = trunc(y[:,1]); true_label = y
// ---------------------------------------------------------------------------
__global__ __launch_bounds__(256) void k_tail(
    const float* __restrict__ y, const float* __restrict__ b1,
    float* __restrict__ out)
{
    int i = blockIdx.x * 256 + threadIdx.x;
    if (i >= N_NODES) return;
    float y0 = y[(size_t)i * 2 + 0];
    float y1 = y[(size_t)i * 2 + 1];
    out[i] = b1[0];
    out[N_NODES + i] = (float)(int)y1;
    out[2 * N_NODES + 2 * i + 0] = y0;
    out[2 * N_NODES + 2 * i + 1] = y1;
}

extern "C" void kernel_launch(void* const* d_in, const int* in_sizes, int n_in,
                              void* d_out, int out_size, void* d_ws, size_t ws_size,
                              hipStream_t stream) {
    const float* node_attr = (const float*)d_in[0];
    const float* y         = (const float*)d_in[1];
    const float* node_emb  = (const float*)d_in[2];
    const float* net_W     = (const float*)d_in[4];
    const float* net_b     = (const float*)d_in[5];
    const float* dev_W     = (const float*)d_in[6];
    const float* dev_b     = (const float*)d_in[7];
    const float* pin_emb   = (const float*)d_in[8];
    const float* sage_Wl   = (const float*)d_in[9];
    const float* sage_bl   = (const float*)d_in[10];
    const float* sage_Wr   = (const float*)d_in[11];
    const float* head_W0   = (const float*)d_in[12];
    const float* head_b0   = (const float*)d_in[13];
    const float* head_W1   = (const float*)d_in[14];
    const float* head_b1   = (const float*)d_in[15];
    const int*   node_type = (const int*)d_in[16];
    const int*   edge_idx  = (const int*)d_in[18];
    float* out = (float*)d_out;

    const size_t xelems = (size_t)N_NODES * HID;
    char* p = (char*)d_ws;
    __hip_bfloat16* x0  = (__hip_bfloat16*)p;  p += xelems * 2;
    __hip_bfloat16* x1  = (__hip_bfloat16*)p;  p += xelems * 2;
    __hip_bfloat16* agg = (__hip_bfloat16*)p;  p += xelems * 2;
    __hip_bfloat16* Wt  = (__hip_bfloat16*)p;  p += (size_t)3 * 256 * 512 * 2;
    __hip_bfloat16* Wh  = (__hip_bfloat16*)p;  p += (size_t)256 * 256 * 2;
    int* deg    = (int*)p; p += N_NODES * 4;
    int* off    = (int*)p; p += N_NODES * 4;
    int* cursor = (int*)p; p += N_NODES * 4;
    int* slots  = (int*)p; p += N_EDGES * 4;
    int* total  = (int*)p; p += 16;

    hipMemsetAsync(deg, 0, N_NODES * sizeof(int), stream);
    hipMemsetAsync(total, 0, sizeof(int), stream);

    k_prep<<<(3 * 131072 + 65536 + 255) / 256, 256, 0, stream>>>(
        sage_Wl, sage_Wr, head_W0, Wt, Wh);
    k_init<<<(N_NODES * NE + 255) / 256, 256, 0, stream>>>(
        node_attr, node_emb, net_W, net_b, dev_W, dev_b, pin_emb, node_type, x0);
    k_tail<<<(N_NODES + 255) / 256, 256, 0, stream>>>(y, head_b1, out);
    k_hist<<<(N_EDGES + 255) / 256, 256, 0, stream>>>(edge_idx, deg);
    k_alloc<<<(N_NODES + 255) / 256, 256, 0, stream>>>(deg, off, cursor, total);
    k_fill<<<(N_EDGES + 255) / 256, 256, 0, stream>>>(edge_idx, cursor, slots);

    const int gemm_grid = (N_NODES + 127) / 128;
    __hip_bfloat16* xcur = x0;
    __hip_bfloat16* xalt = x1;
    for (int l = 0; l < NLAYERS; ++l) {
        k_aggregate<<<(N_NODES * 64 + 255) / 256, 256, 0, stream>>>(
            xcur, off, deg, slots, agg);
        k_mfma<true><<<gemm_grid, 512, 0, stream>>>(
            agg, xcur, Wt + (size_t)l * 131072,
            sage_bl + (size_t)l * HID, nullptr, xalt, nullptr);
        __hip_bfloat16* t = xcur; xcur = xalt; xalt = t;
    }
    k_mfma<false><<<gemm_grid, 512, 0, stream>>>(
        xcur, xcur, Wh, head_b0, head_W1, nullptr, out);
}

// Round 5
// 429.336 us; speedup vs baseline: 11.1890x; 1.2275x over previous
//
#include <hip/hip_runtime.h>
#include <hip/hip_bf16.h>

#define N_NODES 100000
#define N_EDGES 320000
#define HID 256
#define NE 128
#define NLAYERS 3

typedef __attribute__((ext_vector_type(8))) short short8;
typedef __attribute__((ext_vector_type(4))) float f32x4;

__device__ inline float bfbits2f(unsigned int b) { return __uint_as_float(b << 16); }

// ---------------------------------------------------------------------------
// Weight prep: fp32 -> bf16, transposed to [n][k].
// Wt[l][n][k] = (k<256 ? Wl[l][k][n] : Wr[l][k-256][n]);  Wh[n][k] = W0[k][n]
// ---------------------------------------------------------------------------
__global__ __launch_bounds__(256) void k_prep(
    const float* __restrict__ Wl, const float* __restrict__ Wr,
    const float* __restrict__ W0,
    __hip_bfloat16* __restrict__ Wt, __hip_bfloat16* __restrict__ Wh)
{
    int t = blockIdx.x * 256 + threadIdx.x;
    const int total_sage = 3 * 256 * 512;
    if (t < total_sage) {
        int l = t >> 17;
        int rem = t & 131071;
        int n = rem >> 9;
        int k = rem & 511;
        const float* Wsrc = (k < 256) ? (Wl + (size_t)l * 65536)
                                      : (Wr + (size_t)l * 65536);
        Wt[t] = __float2bfloat16(Wsrc[(k & 255) * 256 + n]);
    } else {
        int u = t - total_sage;
        if (u < 65536) {
            int n = u >> 8, k = u & 255;
            Wh[u] = __float2bfloat16(W0[k * 256 + n]);
        }
    }
}

// ---------------------------------------------------------------------------
// Init: x[n,0:128] = node_emb[type]; x[n,128:256] = per-type attr embedding
// ---------------------------------------------------------------------------
__global__ __launch_bounds__(256) void k_init(
    const float* __restrict__ node_attr,
    const float* __restrict__ node_emb,
    const float* __restrict__ net_W, const float* __restrict__ net_b,
    const float* __restrict__ dev_W, const float* __restrict__ dev_b,
    const float* __restrict__ pin_emb,
    const int*   __restrict__ node_type,
    __hip_bfloat16* __restrict__ x)
{
    int t = blockIdx.x * 256 + threadIdx.x;
    if (t >= N_NODES * NE) return;
    int n = t >> 7;
    int c = t & 127;
    int ty = node_type[n];
    float emb = node_emb[ty * NE + c];
    float a;
    if (ty == 0 || ty == 1) {
        const float* W = (ty == 0) ? net_W : dev_W;
        const float* b = (ty == 0) ? net_b : dev_b;
        float s = b[c];
        const float* ar = node_attr + (size_t)n * 17;
        #pragma unroll
        for (int k = 0; k < 17; ++k) s += ar[k] * W[k * NE + c];
        a = s;
    } else if (ty == 2) {
        int idx = (int)node_attr[(size_t)n * 17];
        a = pin_emb[idx * NE + c];
    } else {
        a = 0.0f;
    }
    x[(size_t)n * HID + c]      = __float2bfloat16(emb);
    x[(size_t)n * HID + NE + c] = __float2bfloat16(a);
}

// ---------------------------------------------------------------------------
// CSR build: histogram -> scan-free chunk allocation -> fill
// ---------------------------------------------------------------------------
__global__ __launch_bounds__(256) void k_hist(
    const int* __restrict__ edge_index, int* __restrict__ deg)
{
    int e = blockIdx.x * 256 + threadIdx.x;
    if (e < N_EDGES) atomicAdd(&deg[edge_index[N_EDGES + e]], 1);
}

__global__ __launch_bounds__(256) void k_alloc(
    const int* __restrict__ deg, int* __restrict__ off,
    int* __restrict__ cursor, int* __restrict__ total)
{
    int n = blockIdx.x * 256 + threadIdx.x;
    int lane = threadIdx.x & 63;
    int d = (n < N_NODES) ? deg[n] : 0;
    int incl = d;
    #pragma unroll
    for (int o = 1; o < 64; o <<= 1) {
        int v = __shfl_up(incl, o, 64);
        if (lane >= o) incl += v;
    }
    int wtot = __shfl(incl, 63, 64);
    int base = 0;
    if (lane == 63) base = atomicAdd(total, wtot);
    base = __shfl(base, 63, 64);
    if (n < N_NODES) {
        int o = base + incl - d;
        off[n] = o;
        cursor[n] = o;
    }
}

__global__ __launch_bounds__(256) void k_fill(
    const int* __restrict__ edge_index, int* __restrict__ cursor,
    int* __restrict__ slots)
{
    int e = blockIdx.x * 256 + threadIdx.x;
    if (e >= N_EDGES) return;
    int s = edge_index[e];
    int d = edge_index[N_EDGES + e];
    int slot = atomicAdd(&cursor[d], 1);
    slots[slot] = s;
}

// ---------------------------------------------------------------------------
// Gather-mean: 4 nodes per wave, 16 lanes x 32B per node, fp32 accumulate.
// ---------------------------------------------------------------------------
__global__ __launch_bounds__(256) void k_aggregate(
    const __hip_bfloat16* __restrict__ x,
    const int* __restrict__ off, const int* __restrict__ deg,
    const int* __restrict__ slots,
    __hip_bfloat16* __restrict__ agg)
{
    int g = blockIdx.x * 256 + threadIdx.x;
    int wid = g >> 6;
    int lane = g & 63;
    int sub = lane >> 4;        // node within wave
    int l16 = lane & 15;        // covers 32B of the 512B row
    int n = wid * 4 + sub;
    bool active = n < N_NODES;
    int o = 0, d = 0;
    if (active) { o = off[n]; d = deg[n]; }
    float acc[16];
    #pragma unroll
    for (int i = 0; i < 16; ++i) acc[i] = 0.0f;
    for (int p = 0; p < d; ++p) {
        int src = slots[o + p];
        const char* rp = (const char*)x + (size_t)src * 512 + l16 * 32;
        uint4 v0 = *(const uint4*)rp;
        uint4 v1 = *(const uint4*)(rp + 16);
        const unsigned int u[8] = {v0.x, v0.y, v0.z, v0.w, v1.x, v1.y, v1.z, v1.w};
        #pragma unroll
        for (int i = 0; i < 8; ++i) {
            acc[2 * i + 0] += bfbits2f(u[i] & 0xffffu);
            acc[2 * i + 1] += __uint_as_float(u[i] & 0xffff0000u);
        }
    }
    if (active) {
        float rs = 1.0f / fmaxf((float)d, 1.0f);
        unsigned int w[8];
        #pragma unroll
        for (int i = 0; i < 8; ++i) {
            __hip_bfloat16 lo = __float2bfloat16(acc[2 * i + 0] * rs);
            __hip_bfloat16 hi = __float2bfloat16(acc[2 * i + 1] * rs);
            w[i] = (unsigned int)*(unsigned short*)&lo |
                   ((unsigned int)*(unsigned short*)&hi << 16);
        }
        uint4 o0 = {w[0], w[1], w[2], w[3]};
        uint4 o1 = {w[4], w[5], w[6], w[7]};
        char* op = (char*)agg + (size_t)n * 512 + l16 * 32;
        *(uint4*)op = o0;
        *(uint4*)(op + 16) = o1;
    }
}

// ---------------------------------------------------------------------------
// MFMA layer.  Block 512 thr (8 waves, 1x8): tile 64 rows x 256 cols; each
// wave owns 32 cols (no duplicate B loads).  A staged in LDS (2-deep
// global_load_lds pipeline, XOR-swizzled); B prefetched into registers one
// K-step ahead (ping-pong, fully unrolled).  vmcnt(1) at loop head covers
// A(s)+B(s), leaves A(s+1) staging in flight; vmcnt(0) at final step.
// SAGE: Out = relu([Agg|X] @ Wt^T + bias)   (K=512)
// HEAD: Pred += relu(X @ Wh^T + bias) . W1  (K=256, atomicAdd partials)
// ---------------------------------------------------------------------------
template <bool SAGE>
__global__ __launch_bounds__(512) void k_mfma(
    const __hip_bfloat16* __restrict__ Agg,
    const __hip_bfloat16* __restrict__ X,
    const __hip_bfloat16* __restrict__ Wt,
    const float* __restrict__ bias,
    const float* __restrict__ W1,
    __hip_bfloat16* __restrict__ Out,
    float* __restrict__ Pred)
{
    __shared__ char As[32768];      // staging: 2 x 8KB; epilogue: 64x256 bf16

    const int tid  = threadIdx.x;
    const int w    = tid >> 6, lane = tid & 63;
    const int l15  = lane & 15, lg = lane >> 4;
    const int row0 = blockIdx.x * 64;
    const int KT     = SAGE ? 512 : 256;
    const int nsteps = SAGE ? 8 : 4;

    f32x4 acc[4][2];
    #pragma unroll
    for (int i = 0; i < 4; ++i)
        #pragma unroll
        for (int n = 0; n < 2; ++n) acc[i][n] = (f32x4)0.0f;

    // staging map: 512 thr x 16B = 8KB = one 64x128B tile
    const int srow   = tid >> 3;
    const int schunk = tid & 7;
    int sgrow = row0 + srow; if (sgrow >= N_NODES) sgrow = N_NODES - 1;

    auto stage = [&](int s, int b) {
        const char* base;
        int k0;
        if (SAGE && s < 4) { base = (const char*)Agg; k0 = s * 64; }
        else               { base = (const char*)X;   k0 = (SAGE ? s - 4 : s) * 64; }
        const char* gp = base + (size_t)sgrow * 512 + (size_t)k0 * 2
                       + ((schunk ^ (srow & 7)) << 4);     // inverse swizzle on src
        const char* lp = &As[b * 8192 + tid * 16];         // linear dest
        __builtin_amdgcn_global_load_lds(
            (const __attribute__((address_space(1))) void*)gp,
            (__attribute__((address_space(3))) void*)lp, 16, 0, 0);
    };

    auto loadB = [&](int s, short8 (&bb)[2][2]) {
        #pragma unroll
        for (int h = 0; h < 2; ++h)
            #pragma unroll
            for (int n = 0; n < 2; ++n) {
                int c = w * 32 + n * 16 + l15;
                bb[h][n] = *(const short8*)(Wt + (size_t)c * KT + s * 64 + h * 32 + 8 * lg);
            }
    };

    auto do_step = [&](int s, bool last, short8 (&bcur)[2][2], short8 (&bnxt)[2][2]) {
        const int b = s & 1;
        if (last) asm volatile("s_waitcnt vmcnt(0)" ::: "memory");
        else      asm volatile("s_waitcnt vmcnt(1)" ::: "memory");
        __builtin_amdgcn_sched_barrier(0);
        __builtin_amdgcn_s_barrier();
        __builtin_amdgcn_sched_barrier(0);
        if (!last) loadB(s + 1, bnxt);          // B prefetch, off critical path
        #pragma unroll
        for (int h = 0; h < 2; ++h) {
            short8 a[4];
            #pragma unroll
            for (int i = 0; i < 4; ++i) {
                int r = i * 16 + l15;
                a[i] = *(const short8*)&As[b * 8192 + r * 128 + (((lg + 4 * h) ^ (r & 7)) << 4)];
            }
            #pragma unroll
            for (int i = 0; i < 4; ++i)
                #pragma unroll
                for (int n = 0; n < 2; ++n)
                    acc[i][n] = __builtin_amdgcn_mfma_f32_16x16x32_bf16(
                        a[i], bcur[h][n], acc[i][n], 0, 0, 0);
        }
        __builtin_amdgcn_sched_barrier(0);
        __builtin_amdgcn_s_barrier();           // all waves done reading As[b]
        __builtin_amdgcn_sched_barrier(0);
        if (s + 2 < nsteps) stage(s + 2, b);
    };

    short8 b0[2][2], b1[2][2];
    loadB(0, b0);
    stage(0, 0);
    stage(1, 1);
    #pragma unroll
    for (int s = 0; s < nsteps; s += 2) {
        do_step(s,     s == nsteps - 1, b0, b1);
        do_step(s + 1, s + 1 == nsteps - 1, b1, b0);
    }

    if (SAGE) {
        // Epilogue via LDS for coalesced 16B stores (64x256 bf16 = 32KB)
        __hip_bfloat16* lo = (__hip_bfloat16*)As;
        #pragma unroll
        for (int n = 0; n < 2; ++n) {
            int c = w * 32 + n * 16 + l15;
            float bv = bias[c];
            #pragma unroll
            for (int i = 0; i < 4; ++i)
                #pragma unroll
                for (int r = 0; r < 4; ++r) {
                    int rl = i * 16 + lg * 4 + r;
                    lo[rl * 256 + c] = __float2bfloat16(fmaxf(acc[i][n][r] + bv, 0.0f));
                }
        }
        __syncthreads();
        #pragma unroll
        for (int q = 0; q < 4; ++q) {
            int chunk = tid + q * 512;          // 2048 x 16B = 64 rows x 512B
            int rl = chunk >> 5, cc = chunk & 31;
            int grow = row0 + rl;
            if (grow < N_NODES)
                *(uint4*)((char*)Out + (size_t)grow * 512 + cc * 16) =
                    *(const uint4*)((const char*)As + rl * 512 + cc * 16);
        }
    } else {
        float p[4][4];
        #pragma unroll
        for (int i = 0; i < 4; ++i)
            #pragma unroll
            for (int r = 0; r < 4; ++r) p[i][r] = 0.0f;
        #pragma unroll
        for (int n = 0; n < 2; ++n) {
            int c = w * 32 + n * 16 + l15;
            float bv = bias[c];
            float wv = W1[c];
            #pragma unroll
            for (int i = 0; i < 4; ++i)
                #pragma unroll
                for (int r = 0; r < 4; ++r)
                    p[i][r] += fmaxf(acc[i][n][r] + bv, 0.0f) * wv;
        }
        #pragma unroll
        for (int i = 0; i < 4; ++i)
            #pragma unroll
            for (int r = 0; r < 4; ++r) {
                float s = p[i][r];
                #pragma unroll
                for (int m = 1; m < 16; m <<= 1) s += __shfl_xor(s, m, 64);
                if (l15 == 0) {
                    int row = row0 + i * 16 + lg * 4 + r;
                    if (row < N_NODES) atomicAdd(&Pred[row], s);
                }
            }
    }
}

// ---------------------------------------------------------------------------
// Tail: pred init = b1; true_class = trunc(y[:,1]); true_label = y
// ---------------------------------------------------------------------------
__global__ __launch_bounds__(256) void k_tail(
    const float* __restrict__ y, const float* __restrict__ b1,
    float* __restrict__ out)
{
    int i = blockIdx.x * 256 + threadIdx.x;
    if (i >= N_NODES) return;
    float y0 = y[(size_t)i * 2 + 0];
    float y1 = y[(size_t)i * 2 + 1];
    out[i] = b1[0];
    out[N_NODES + i] = (float)(int)y1;
    out[2 * N_NODES + 2 * i + 0] = y0;
    out[2 * N_NODES + 2 * i + 1] = y1;
}

extern "C" void kernel_launch(void* const* d_in, const int* in_sizes, int n_in,
                              void* d_out, int out_size, void* d_ws, size_t ws_size,
                              hipStream_t stream) {
    const float* node_attr = (const float*)d_in[0];
    const float* y         = (const float*)d_in[1];
    const float* node_emb  = (const float*)d_in[2];
    const float* net_W     = (const float*)d_in[4];
    const float* net_b     = (const float*)d_in[5];
    const float* dev_W     = (const float*)d_in[6];
    const float* dev_b     = (const float*)d_in[7];
    const float* pin_emb   = (const float*)d_in[8];
    const float* sage_Wl   = (const float*)d_in[9];
    const float* sage_bl   = (const float*)d_in[10];
    const float* sage_Wr   = (const float*)d_in[11];
    const float* head_W0   = (const float*)d_in[12];
    const float* head_b0   = (const float*)d_in[13];
    const float* head_W1   = (const float*)d_in[14];
    const float* head_b1   = (const float*)d_in[15];
    const int*   node_type = (const int*)d_in[16];
    const int*   edge_idx  = (const int*)d_in[18];
    float* out = (float*)d_out;

    const size_t xelems = (size_t)N_NODES * HID;
    char* p = (char*)d_ws;
    __hip_bfloat16* x0  = (__hip_bfloat16*)p;  p += xelems * 2;
    __hip_bfloat16* x1  = (__hip_bfloat16*)p;  p += xelems * 2;
    __hip_bfloat16* agg = (__hip_bfloat16*)p;  p += xelems * 2;
    __hip_bfloat16* Wt  = (__hip_bfloat16*)p;  p += (size_t)3 * 256 * 512 * 2;
    __hip_bfloat16* Wh  = (__hip_bfloat16*)p;  p += (size_t)256 * 256 * 2;
    int* deg    = (int*)p; p += N_NODES * 4;
    int* off    = (int*)p; p += N_NODES * 4;
    int* cursor = (int*)p; p += N_NODES * 4;
    int* slots  = (int*)p; p += N_EDGES * 4;
    int* total  = (int*)p; p += 16;

    hipMemsetAsync(deg, 0, N_NODES * sizeof(int), stream);
    hipMemsetAsync(total, 0, sizeof(int), stream);

    k_prep<<<(3 * 131072 + 65536 + 255) / 256, 256, 0, stream>>>(
        sage_Wl, sage_Wr, head_W0, Wt, Wh);
    k_init<<<(N_NODES * NE + 255) / 256, 256, 0, stream>>>(
        node_attr, node_emb, net_W, net_b, dev_W, dev_b, pin_emb, node_type, x0);
    k_tail<<<(N_NODES + 255) / 256, 256, 0, stream>>>(y, head_b1, out);
    k_hist<<<(N_EDGES + 255) / 256, 256, 0, stream>>>(edge_idx, deg);
    k_alloc<<<(N_NODES + 255) / 256, 256, 0, stream>>>(deg, off, cursor, total);
    k_fill<<<(N_EDGES + 255) / 256, 256, 0, stream>>>(edge_idx, cursor, slots);

    const int gemm_grid = (N_NODES + 63) / 64;
    __hip_bfloat16* xcur = x0;
    __hip_bfloat16* xalt = x1;
    for (int l = 0; l < NLAYERS; ++l) {
        k_aggregate<<<(N_NODES / 4 * 64 + 255) / 256, 256, 0, stream>>>(
            xcur, off, deg, slots, agg);
        k_mfma<true><<<gemm_grid, 512, 0, stream>>>(
            agg, xcur, Wt + (size_t)l * 131072,
            sage_bl + (size_t)l * HID, nullptr, xalt, nullptr);
        __hip_bfloat16* t = xcur; xcur = xalt; xalt = t;
    }
    k_mfma<false><<<gemm_grid, 512, 0, stream>>>(
        xcur, xcur, Wh, head_b0, head_W1, nullptr, out);
}

// Round 6
// 381.521 us; speedup vs baseline: 12.5913x; 1.1253x over previous
//
#include <hip/hip_runtime.h>
#include <hip/hip_bf16.h>

#define N_NODES 100000
#define N_EDGES 320000
#define HID 256
#define NE 128
#define NLAYERS 3

typedef __attribute__((ext_vector_type(8))) short short8;
typedef __attribute__((ext_vector_type(4))) float f32x4;

__device__ inline float bfbits2f(unsigned int b) { return __uint_as_float(b << 16); }

// ---------------------------------------------------------------------------
// Weight prep: fp32 -> bf16, transposed to [n][k].  Also zeroes deg/total
// (saves two hipMemsetAsync dispatches; k_hist runs after us on the stream).
// ---------------------------------------------------------------------------
__global__ __launch_bounds__(256) void k_prep(
    const float* __restrict__ Wl, const float* __restrict__ Wr,
    const float* __restrict__ W0,
    __hip_bfloat16* __restrict__ Wt, __hip_bfloat16* __restrict__ Wh,
    int* __restrict__ deg, int* __restrict__ total)
{
    int t = blockIdx.x * 256 + threadIdx.x;
    const int total_sage = 3 * 256 * 512;
    if (t < total_sage) {
        int l = t >> 17;
        int rem = t & 131071;
        int n = rem >> 9;
        int k = rem & 511;
        const float* Wsrc = (k < 256) ? (Wl + (size_t)l * 65536)
                                      : (Wr + (size_t)l * 65536);
        Wt[t] = __float2bfloat16(Wsrc[(k & 255) * 256 + n]);
    } else {
        int u = t - total_sage;
        if (u < 65536) {
            int n = u >> 8, k = u & 255;
            Wh[u] = __float2bfloat16(W0[k * 256 + n]);
        }
    }
    if (t < N_NODES) deg[t] = 0;
    if (t == 0) *total = 0;
}

// ---------------------------------------------------------------------------
// Init: x rows + (c==0 lanes) the output tail: pred=b1, true_class, true_label
// ---------------------------------------------------------------------------
__global__ __launch_bounds__(256) void k_init(
    const float* __restrict__ node_attr,
    const float* __restrict__ node_emb,
    const float* __restrict__ net_W, const float* __restrict__ net_b,
    const float* __restrict__ dev_W, const float* __restrict__ dev_b,
    const float* __restrict__ pin_emb,
    const int*   __restrict__ node_type,
    const float* __restrict__ y, const float* __restrict__ b1,
    float* __restrict__ out,
    __hip_bfloat16* __restrict__ x)
{
    int t = blockIdx.x * 256 + threadIdx.x;
    if (t >= N_NODES * NE) return;
    int n = t >> 7;
    int c = t & 127;
    int ty = node_type[n];
    float emb = node_emb[ty * NE + c];
    float a;
    if (ty == 0 || ty == 1) {
        const float* W = (ty == 0) ? net_W : dev_W;
        const float* b = (ty == 0) ? net_b : dev_b;
        float s = b[c];
        const float* ar = node_attr + (size_t)n * 17;
        #pragma unroll
        for (int k = 0; k < 17; ++k) s += ar[k] * W[k * NE + c];
        a = s;
    } else if (ty == 2) {
        int idx = (int)node_attr[(size_t)n * 17];
        a = pin_emb[idx * NE + c];
    } else {
        a = 0.0f;
    }
    x[(size_t)n * HID + c]      = __float2bfloat16(emb);
    x[(size_t)n * HID + NE + c] = __float2bfloat16(a);
    if (c == 0) {
        float y0 = y[(size_t)n * 2 + 0];
        float y1 = y[(size_t)n * 2 + 1];
        out[n] = b1[0];
        out[N_NODES + n] = (float)(int)y1;
        out[2 * N_NODES + 2 * n + 0] = y0;
        out[2 * N_NODES + 2 * n + 1] = y1;
    }
}

// ---------------------------------------------------------------------------
// CSR build: histogram -> scan-free chunk allocation -> fill
// ---------------------------------------------------------------------------
__global__ __launch_bounds__(256) void k_hist(
    const int* __restrict__ edge_index, int* __restrict__ deg)
{
    int e = blockIdx.x * 256 + threadIdx.x;
    if (e < N_EDGES) atomicAdd(&deg[edge_index[N_EDGES + e]], 1);
}

__global__ __launch_bounds__(256) void k_alloc(
    const int* __restrict__ deg, int* __restrict__ off,
    int* __restrict__ cursor, int* __restrict__ total)
{
    int n = blockIdx.x * 256 + threadIdx.x;
    int lane = threadIdx.x & 63;
    int d = (n < N_NODES) ? deg[n] : 0;
    int incl = d;
    #pragma unroll
    for (int o = 1; o < 64; o <<= 1) {
        int v = __shfl_up(incl, o, 64);
        if (lane >= o) incl += v;
    }
    int wtot = __shfl(incl, 63, 64);
    int base = 0;
    if (lane == 63) base = atomicAdd(total, wtot);
    base = __shfl(base, 63, 64);
    if (n < N_NODES) {
        int o = base + incl - d;
        off[n] = o;
        cursor[n] = o;
    }
}

__global__ __launch_bounds__(256) void k_fill(
    const int* __restrict__ edge_index, int* __restrict__ cursor,
    int* __restrict__ slots)
{
    int e = blockIdx.x * 256 + threadIdx.x;
    if (e >= N_EDGES) return;
    int s = edge_index[e];
    int d = edge_index[N_EDGES + e];
    int slot = atomicAdd(&cursor[d], 1);
    slots[slot] = s;
}

// ---------------------------------------------------------------------------
// Gather-mean: 4 nodes per wave, 16 lanes x 32B per node, fp32 accumulate.
// ---------------------------------------------------------------------------
__global__ __launch_bounds__(256) void k_aggregate(
    const __hip_bfloat16* __restrict__ x,
    const int* __restrict__ off, const int* __restrict__ deg,
    const int* __restrict__ slots,
    __hip_bfloat16* __restrict__ agg)
{
    int g = blockIdx.x * 256 + threadIdx.x;
    int wid = g >> 6;
    int lane = g & 63;
    int sub = lane >> 4;        // node within wave
    int l16 = lane & 15;        // covers 32B of the 512B row
    int n = wid * 4 + sub;
    bool active = n < N_NODES;
    int o = 0, d = 0;
    if (active) { o = off[n]; d = deg[n]; }
    float acc[16];
    #pragma unroll
    for (int i = 0; i < 16; ++i) acc[i] = 0.0f;
    for (int p = 0; p < d; ++p) {
        int src = slots[o + p];
        const char* rp = (const char*)x + (size_t)src * 512 + l16 * 32;
        uint4 v0 = *(const uint4*)rp;
        uint4 v1 = *(const uint4*)(rp + 16);
        const unsigned int u[8] = {v0.x, v0.y, v0.z, v0.w, v1.x, v1.y, v1.z, v1.w};
        #pragma unroll
        for (int i = 0; i < 8; ++i) {
            acc[2 * i + 0] += bfbits2f(u[i] & 0xffffu);
            acc[2 * i + 1] += __uint_as_float(u[i] & 0xffff0000u);
        }
    }
    if (active) {
        float rs = 1.0f / fmaxf((float)d, 1.0f);
        unsigned int w[8];
        #pragma unroll
        for (int i = 0; i < 8; ++i) {
            __hip_bfloat16 lo = __float2bfloat16(acc[2 * i + 0] * rs);
            __hip_bfloat16 hi = __float2bfloat16(acc[2 * i + 1] * rs);
            w[i] = (unsigned int)*(unsigned short*)&lo |
                   ((unsigned int)*(unsigned short*)&hi << 16);
        }
        uint4 o0 = {w[0], w[1], w[2], w[3]};
        uint4 o1 = {w[4], w[5], w[6], w[7]};
        char* op = (char*)agg + (size_t)n * 512 + l16 * 32;
        *(uint4*)op = o0;
        *(uint4*)(op + 16) = o1;
    }
}

// ---------------------------------------------------------------------------
// MFMA layer.  Block 512 thr (8 waves, 1x8): tile 128 rows x 256 cols; each
// wave owns 32 cols (no duplicate B loads) and all 128 rows (acc 8x2 f32x4).
// A staged in LDS (2-deep global_load_lds pipeline, XOR-swizzled, BK=64 ->
// 16KB/buffer, 2 issues/thread); B prefetched into registers one K-step
// ahead.  vmcnt(2) at loop head leaves next A-stage in flight.
// SAGE: Out = relu([Agg|X] @ Wt^T + bias)   (K=512)
// HEAD: Pred += relu(X @ Wh^T + bias) . W1  (K=256, atomicAdd partials)
// ---------------------------------------------------------------------------
template <bool SAGE>
__global__ __launch_bounds__(512, 4) void k_mfma(
    const __hip_bfloat16* __restrict__ Agg,
    const __hip_bfloat16* __restrict__ X,
    const __hip_bfloat16* __restrict__ Wt,
    const float* __restrict__ bias,
    const float* __restrict__ W1,
    __hip_bfloat16* __restrict__ Out,
    float* __restrict__ Pred)
{
    __shared__ char As[2][16384];   // 2 x (128 rows x 64 k x bf16)

    const int tid  = threadIdx.x;
    const int w    = tid >> 6, lane = tid & 63;
    const int l15  = lane & 15, lg = lane >> 4;
    const int row0 = blockIdx.x * 128;
    const int KT     = SAGE ? 512 : 256;
    const int nsteps = SAGE ? 8 : 4;

    f32x4 acc[8][2];
    #pragma unroll
    for (int i = 0; i < 8; ++i)
        #pragma unroll
        for (int n = 0; n < 2; ++n) acc[i][n] = (f32x4)0.0f;

    // staging map: 512 thr x 16B x 2 issues = 16KB = 128 rows x 128B
    const int srow   = tid >> 3;     // 0..63 (+64 on issue 1)
    const int schunk = tid & 7;

    auto stage = [&](int s, int b) {
        const char* base;
        int k0;
        if (SAGE && s < 4) { base = (const char*)Agg; k0 = s * 64; }
        else               { base = (const char*)X;   k0 = (SAGE ? s - 4 : s) * 64; }
        #pragma unroll
        for (int issue = 0; issue < 2; ++issue) {
            int row  = srow + issue * 64;
            int grow = row0 + row;
            if (grow >= N_NODES) grow = N_NODES - 1;
            const char* gp = base + (size_t)grow * 512 + (size_t)k0 * 2
                           + ((schunk ^ (row & 7)) << 4);      // inverse swizzle
            const char* lp = &As[b][issue * 8192 + tid * 16];  // linear dest
            __builtin_amdgcn_global_load_lds(
                (const __attribute__((address_space(1))) void*)gp,
                (__attribute__((address_space(3))) void*)lp, 16, 0, 0);
        }
    };

    auto loadB = [&](int s, short8 (&bb)[2][2]) {
        #pragma unroll
        for (int h = 0; h < 2; ++h)
            #pragma unroll
            for (int n = 0; n < 2; ++n) {
                int c = w * 32 + n * 16 + l15;
                bb[h][n] = *(const short8*)(Wt + (size_t)c * KT + s * 64 + h * 32 + 8 * lg);
            }
    };

    auto do_step = [&](int s, bool last, short8 (&bcur)[2][2], short8 (&bnxt)[2][2]) {
        const int b = s & 1;
        if (last) asm volatile("s_waitcnt vmcnt(0)" ::: "memory");
        else      asm volatile("s_waitcnt vmcnt(2)" ::: "memory");
        __builtin_amdgcn_sched_barrier(0);
        __builtin_amdgcn_s_barrier();
        __builtin_amdgcn_sched_barrier(0);
        if (!last) loadB(s + 1, bnxt);          // B prefetch, off critical path
        #pragma unroll
        for (int h = 0; h < 2; ++h) {
            #pragma unroll
            for (int i = 0; i < 8; ++i) {
                int r = i * 16 + l15;
                short8 a = *(const short8*)&As[b][r * 128 + (((lg + 4 * h) ^ (r & 7)) << 4)];
                acc[i][0] = __builtin_amdgcn_mfma_f32_16x16x32_bf16(a, bcur[h][0], acc[i][0], 0, 0, 0);
                acc[i][1] = __builtin_amdgcn_mfma_f32_16x16x32_bf16(a, bcur[h][1], acc[i][1], 0, 0, 0);
            }
        }
        __builtin_amdgcn_sched_barrier(0);
        __builtin_amdgcn_s_barrier();           // all waves done reading As[b]
        __builtin_amdgcn_sched_barrier(0);
        if (s + 2 < nsteps) stage(s + 2, b);
    };

    short8 b0[2][2], b1[2][2];
    loadB(0, b0);
    stage(0, 0);
    stage(1, 1);
    #pragma unroll
    for (int s = 0; s < nsteps; s += 2) {
        do_step(s,     s == nsteps - 1, b0, b1);
        do_step(s + 1, s + 1 == nsteps - 1, b1, b0);
    }

    if (SAGE) {
        // Epilogue: two 64-row halves through the 32KB LDS, coalesced stores
        __hip_bfloat16* lo = (__hip_bfloat16*)As;
        #pragma unroll
        for (int hh = 0; hh < 2; ++hh) {
            #pragma unroll
            for (int n = 0; n < 2; ++n) {
                int c = w * 32 + n * 16 + l15;
                float bv = bias[c];
                #pragma unroll
                for (int i2 = 0; i2 < 4; ++i2) {
                    int i = hh * 4 + i2;
                    #pragma unroll
                    for (int r = 0; r < 4; ++r) {
                        int rl = i2 * 16 + lg * 4 + r;
                        lo[rl * 256 + c] = __float2bfloat16(fmaxf(acc[i][n][r] + bv, 0.0f));
                    }
                }
            }
            __syncthreads();
            #pragma unroll
            for (int q = 0; q < 4; ++q) {
                int chunk = tid + q * 512;      // 2048 x 16B = 64 rows x 512B
                int rl = chunk >> 5, cc = chunk & 31;
                int grow = row0 + hh * 64 + rl;
                if (grow < N_NODES)
                    *(uint4*)((char*)Out + (size_t)grow * 512 + cc * 16) =
                        *(const uint4*)((const char*)As + rl * 512 + cc * 16);
            }
            __syncthreads();
        }
    } else {
        #pragma unroll
        for (int i = 0; i < 8; ++i) {
            float p[4];
            #pragma unroll
            for (int r = 0; r < 4; ++r) p[r] = 0.0f;
            #pragma unroll
            for (int n = 0; n < 2; ++n) {
                int c = w * 32 + n * 16 + l15;
                float bv = bias[c];
                float wv = W1[c];
                #pragma unroll
                for (int r = 0; r < 4; ++r)
                    p[r] += fmaxf(acc[i][n][r] + bv, 0.0f) * wv;
            }
            #pragma unroll
            for (int r = 0; r < 4; ++r) {
                float s = p[r];
                #pragma unroll
                for (int m = 1; m < 16; m <<= 1) s += __shfl_xor(s, m, 64);
                if (l15 == 0) {
                    int row = row0 + i * 16 + lg * 4 + r;
                    if (row < N_NODES) atomicAdd(&Pred[row], s);
                }
            }
        }
    }
}

extern "C" void kernel_launch(void* const* d_in, const int* in_sizes, int n_in,
                              void* d_out, int out_size, void* d_ws, size_t ws_size,
                              hipStream_t stream) {
    const float* node_attr = (const float*)d_in[0];
    const float* y         = (const float*)d_in[1];
    const float* node_emb  = (const float*)d_in[2];
    const float* net_W     = (const float*)d_in[4];
    const float* net_b     = (const float*)d_in[5];
    const float* dev_W     = (const float*)d_in[6];
    const float* dev_b     = (const float*)d_in[7];
    const float* pin_emb   = (const float*)d_in[8];
    const float* sage_Wl   = (const float*)d_in[9];
    const float* sage_bl   = (const float*)d_in[10];
    const float* sage_Wr   = (const float*)d_in[11];
    const float* head_W0   = (const float*)d_in[12];
    const float* head_b0   = (const float*)d_in[13];
    const float* head_W1   = (const float*)d_in[14];
    const float* head_b1   = (const float*)d_in[15];
    const int*   node_type = (const int*)d_in[16];
    const int*   edge_idx  = (const int*)d_in[18];
    float* out = (float*)d_out;

    const size_t xelems = (size_t)N_NODES * HID;
    char* p = (char*)d_ws;
    __hip_bfloat16* x0  = (__hip_bfloat16*)p;  p += xelems * 2;
    __hip_bfloat16* x1  = (__hip_bfloat16*)p;  p += xelems * 2;
    __hip_bfloat16* agg = (__hip_bfloat16*)p;  p += xelems * 2;
    __hip_bfloat16* Wt  = (__hip_bfloat16*)p;  p += (size_t)3 * 256 * 512 * 2;
    __hip_bfloat16* Wh  = (__hip_bfloat16*)p;  p += (size_t)256 * 256 * 2;
    int* deg    = (int*)p; p += N_NODES * 4;
    int* off    = (int*)p; p += N_NODES * 4;
    int* cursor = (int*)p; p += N_NODES * 4;
    int* slots  = (int*)p; p += N_EDGES * 4;
    int* total  = (int*)p; p += 16;

    k_prep<<<(3 * 131072 + 65536 + 255) / 256, 256, 0, stream>>>(
        sage_Wl, sage_Wr, head_W0, Wt, Wh, deg, total);
    k_init<<<(N_NODES * NE + 255) / 256, 256, 0, stream>>>(
        node_attr, node_emb, net_W, net_b, dev_W, dev_b, pin_emb, node_type,
        y, head_b1, out, x0);
    k_hist<<<(N_EDGES + 255) / 256, 256, 0, stream>>>(edge_idx, deg);
    k_alloc<<<(N_NODES + 255) / 256, 256, 0, stream>>>(deg, off, cursor, total);
    k_fill<<<(N_EDGES + 255) / 256, 256, 0, stream>>>(edge_idx, cursor, slots);

    const int gemm_grid = (N_NODES + 127) / 128;
    __hip_bfloat16* xcur = x0;
    __hip_bfloat16* xalt = x1;
    for (int l = 0; l < NLAYERS; ++l) {
        k_aggregate<<<(N_NODES / 4 * 64 + 255) / 256, 256, 0, stream>>>(
            xcur, off, deg, slots, agg);
        k_mfma<true><<<gemm_grid, 512, 0, stream>>>(
            agg, xcur, Wt + (size_t)l * 131072,
            sage_bl + (size_t)l * HID, nullptr, xalt, nullptr);
        __hip_bfloat16* t = xcur; xcur = xalt; xalt = t;
    }
    k_mfma<false><<<gemm_grid, 512, 0, stream>>>(
        xcur, xcur, Wh, head_b0, head_W1, nullptr, out);
}

// Round 7
// 360.140 us; speedup vs baseline: 13.3388x; 1.0594x over previous
//
#include <hip/hip_runtime.h>
#include <hip/hip_bf16.h>

#define N_NODES 100000
#define N_EDGES 320000
#define HID 256
#define NE 128
#define NLAYERS 3

typedef __attribute__((ext_vector_type(8))) short short8;
typedef __attribute__((ext_vector_type(4))) float f32x4;

__device__ inline float bfbits2f(unsigned int b) { return __uint_as_float(b << 16); }

__device__ inline unsigned int pack_bf2(float lo, float hi) {
    __hip_bfloat16 l = __float2bfloat16(lo), h = __float2bfloat16(hi);
    return (unsigned int)*(unsigned short*)&l |
           ((unsigned int)*(unsigned short*)&h << 16);
}

// ---------------------------------------------------------------------------
// Weight prep: fp32 -> bf16, transposed to [n][k].  Also zeroes deg/total
// (saves two hipMemsetAsync dispatches; k_hist runs after us on the stream).
// ---------------------------------------------------------------------------
__global__ __launch_bounds__(256) void k_prep(
    const float* __restrict__ Wl, const float* __restrict__ Wr,
    const float* __restrict__ W0,
    __hip_bfloat16* __restrict__ Wt, __hip_bfloat16* __restrict__ Wh,
    int* __restrict__ deg, int* __restrict__ total)
{
    int t = blockIdx.x * 256 + threadIdx.x;
    const int total_sage = 3 * 256 * 512;
    if (t < total_sage) {
        int l = t >> 17;
        int rem = t & 131071;
        int n = rem >> 9;
        int k = rem & 511;
        const float* Wsrc = (k < 256) ? (Wl + (size_t)l * 65536)
                                      : (Wr + (size_t)l * 65536);
        Wt[t] = __float2bfloat16(Wsrc[(k & 255) * 256 + n]);
    } else {
        int u = t - total_sage;
        if (u < 65536) {
            int n = u >> 8, k = u & 255;
            Wh[u] = __float2bfloat16(W0[k * 256 + n]);
        }
    }
    if (t < N_NODES) deg[t] = 0;
    if (t == 0) *total = 0;
}

// ---------------------------------------------------------------------------
// Init (vectorized): 32 threads/node, each handles 4 emb cols + 4 attr cols,
// 8B uint2 stores.  Trailing blocks (t >= N*32) write the output tail.
// ---------------------------------------------------------------------------
__global__ __launch_bounds__(256) void k_init(
    const float* __restrict__ node_attr,
    const float* __restrict__ node_emb,
    const float* __restrict__ net_W, const float* __restrict__ net_b,
    const float* __restrict__ dev_W, const float* __restrict__ dev_b,
    const float* __restrict__ pin_emb,
    const int*   __restrict__ node_type,
    const float* __restrict__ y, const float* __restrict__ b1,
    float* __restrict__ out,
    __hip_bfloat16* __restrict__ x)
{
    int t = blockIdx.x * 256 + threadIdx.x;
    if (t < N_NODES * 32) {
        int n  = t >> 5;
        int c4 = (t & 31) * 4;
        int ty = node_type[n];
        float4 e = *(const float4*)(node_emb + ty * NE + c4);
        float4 a;
        if (ty == 0 || ty == 1) {
            const float* W = (ty == 0) ? net_W : dev_W;
            const float* b = (ty == 0) ? net_b : dev_b;
            a = *(const float4*)(b + c4);
            const float* ar = node_attr + (size_t)n * 17;
            #pragma unroll
            for (int k = 0; k < 17; ++k) {
                float av = ar[k];
                float4 wv = *(const float4*)(W + k * NE + c4);
                a.x += av * wv.x; a.y += av * wv.y;
                a.z += av * wv.z; a.w += av * wv.w;
            }
        } else if (ty == 2) {
            int idx = (int)node_attr[(size_t)n * 17];
            a = *(const float4*)(pin_emb + idx * NE + c4);
        } else {
            a.x = a.y = a.z = a.w = 0.0f;
        }
        uint2 ev = {pack_bf2(e.x, e.y), pack_bf2(e.z, e.w)};
        uint2 av = {pack_bf2(a.x, a.y), pack_bf2(a.z, a.w)};
        *(uint2*)((char*)x + (size_t)n * 512 + c4 * 2)       = ev;
        *(uint2*)((char*)x + (size_t)n * 512 + 256 + c4 * 2) = av;
    } else {
        int n = t - N_NODES * 32;
        if (n < N_NODES) {
            float y0 = y[(size_t)n * 2 + 0];
            float y1 = y[(size_t)n * 2 + 1];
            out[n] = b1[0];
            out[N_NODES + n] = (float)(int)y1;
            out[2 * N_NODES + 2 * n + 0] = y0;
            out[2 * N_NODES + 2 * n + 1] = y1;
        }
    }
}

// ---------------------------------------------------------------------------
// CSR build: histogram -> scan-free chunk allocation -> fill
// ---------------------------------------------------------------------------
__global__ __launch_bounds__(256) void k_hist(
    const int* __restrict__ edge_index, int* __restrict__ deg)
{
    int e = blockIdx.x * 256 + threadIdx.x;
    if (e < N_EDGES) atomicAdd(&deg[edge_index[N_EDGES + e]], 1);
}

__global__ __launch_bounds__(256) void k_alloc(
    const int* __restrict__ deg, int* __restrict__ off,
    int* __restrict__ cursor, int* __restrict__ total)
{
    int n = blockIdx.x * 256 + threadIdx.x;
    int lane = threadIdx.x & 63;
    int d = (n < N_NODES) ? deg[n] : 0;
    int incl = d;
    #pragma unroll
    for (int o = 1; o < 64; o <<= 1) {
        int v = __shfl_up(incl, o, 64);
        if (lane >= o) incl += v;
    }
    int wtot = __shfl(incl, 63, 64);
    int base = 0;
    if (lane == 63) base = atomicAdd(total, wtot);
    base = __shfl(base, 63, 64);
    if (n < N_NODES) {
        int o = base + incl - d;
        off[n] = o;
        cursor[n] = o;
    }
}

__global__ __launch_bounds__(256) void k_fill(
    const int* __restrict__ edge_index, int* __restrict__ cursor,
    int* __restrict__ slots)
{
    int e = blockIdx.x * 256 + threadIdx.x;
    if (e >= N_EDGES) return;
    int s = edge_index[e];
    int d = edge_index[N_EDGES + e];
    int slot = atomicAdd(&cursor[d], 1);
    slots[slot] = s;
}

// ---------------------------------------------------------------------------
// Gather-mean: 4 nodes per wave, 16 lanes x 32B per node, fp32 accumulate.
// ---------------------------------------------------------------------------
__global__ __launch_bounds__(256) void k_aggregate(
    const __hip_bfloat16* __restrict__ x,
    const int* __restrict__ off, const int* __restrict__ deg,
    const int* __restrict__ slots,
    __hip_bfloat16* __restrict__ agg)
{
    int g = blockIdx.x * 256 + threadIdx.x;
    int wid = g >> 6;
    int lane = g & 63;
    int sub = lane >> 4;        // node within wave
    int l16 = lane & 15;        // covers 32B of the 512B row
    int n = wid * 4 + sub;
    bool active = n < N_NODES;
    int o = 0, d = 0;
    if (active) { o = off[n]; d = deg[n]; }
    float acc[16];
    #pragma unroll
    for (int i = 0; i < 16; ++i) acc[i] = 0.0f;
    for (int p = 0; p < d; ++p) {
        int src = slots[o + p];
        const char* rp = (const char*)x + (size_t)src * 512 + l16 * 32;
        uint4 v0 = *(const uint4*)rp;
        uint4 v1 = *(const uint4*)(rp + 16);
        const unsigned int u[8] = {v0.x, v0.y, v0.z, v0.w, v1.x, v1.y, v1.z, v1.w};
        #pragma unroll
        for (int i = 0; i < 8; ++i) {
            acc[2 * i + 0] += bfbits2f(u[i] & 0xffffu);
            acc[2 * i + 1] += __uint_as_float(u[i] & 0xffff0000u);
        }
    }
    if (active) {
        float rs = 1.0f / fmaxf((float)d, 1.0f);
        unsigned int w[8];
        #pragma unroll
        for (int i = 0; i < 8; ++i)
            w[i] = pack_bf2(acc[2 * i + 0] * rs, acc[2 * i + 1] * rs);
        uint4 o0 = {w[0], w[1], w[2], w[3]};
        uint4 o1 = {w[4], w[5], w[6], w[7]};
        char* op = (char*)agg + (size_t)n * 512 + l16 * 32;
        *(uint4*)op = o0;
        *(uint4*)(op + 16) = o1;
    }
}

// ---------------------------------------------------------------------------
// MFMA layer.  Block 512 thr (8 waves, 1x8): tile 128 rows x 256 cols; each
// wave owns 32 cols (no duplicate B loads) and all 128 rows (acc 8x2 f32x4).
// A staged in LDS (2-deep global_load_lds pipeline, XOR-swizzled, BK=64 ->
// 16KB/buffer, 2 issues/thread); B prefetched into registers one K-step
// ahead.  vmcnt(2) at loop head leaves next A-stage in flight.
// SAGE: Out = relu([Agg|X] @ Wt^T + bias)   (K=512)
// HEAD: Pred += relu(X @ Wh^T + bias) . W1  (K=256, atomicAdd partials)
// ---------------------------------------------------------------------------
template <bool SAGE>
__global__ __launch_bounds__(512, 4) void k_mfma(
    const __hip_bfloat16* __restrict__ Agg,
    const __hip_bfloat16* __restrict__ X,
    const __hip_bfloat16* __restrict__ Wt,
    const float* __restrict__ bias,
    const float* __restrict__ W1,
    __hip_bfloat16* __restrict__ Out,
    float* __restrict__ Pred)
{
    __shared__ char As[2][16384];   // 2 x (128 rows x 64 k x bf16)

    const int tid  = threadIdx.x;
    const int w    = tid >> 6, lane = tid & 63;
    const int l15  = lane & 15, lg = lane >> 4;
    const int row0 = blockIdx.x * 128;
    const int KT     = SAGE ? 512 : 256;
    const int nsteps = SAGE ? 8 : 4;

    f32x4 acc[8][2];
    #pragma unroll
    for (int i = 0; i < 8; ++i)
        #pragma unroll
        for (int n = 0; n < 2; ++n) acc[i][n] = (f32x4)0.0f;

    // staging map: 512 thr x 16B x 2 issues = 16KB = 128 rows x 128B
    const int srow   = tid >> 3;     // 0..63 (+64 on issue 1)
    const int schunk = tid & 7;

    auto stage = [&](int s, int b) {
        const char* base;
        int k0;
        if (SAGE && s < 4) { base = (const char*)Agg; k0 = s * 64; }
        else               { base = (const char*)X;   k0 = (SAGE ? s - 4 : s) * 64; }
        #pragma unroll
        for (int issue = 0; issue < 2; ++issue) {
            int row  = srow + issue * 64;
            int grow = row0 + row;
            if (grow >= N_NODES) grow = N_NODES - 1;
            const char* gp = base + (size_t)grow * 512 + (size_t)k0 * 2
                           + ((schunk ^ (row & 7)) << 4);      // inverse swizzle
            const char* lp = &As[b][issue * 8192 + tid * 16];  // linear dest
            __builtin_amdgcn_global_load_lds(
                (const __attribute__((address_space(1))) void*)gp,
                (__attribute__((address_space(3))) void*)lp, 16, 0, 0);
        }
    };

    auto loadB = [&](int s, short8 (&bb)[2][2]) {
        #pragma unroll
        for (int h = 0; h < 2; ++h)
            #pragma unroll
            for (int n = 0; n < 2; ++n) {
                int c = w * 32 + n * 16 + l15;
                bb[h][n] = *(const short8*)(Wt + (size_t)c * KT + s * 64 + h * 32 + 8 * lg);
            }
    };

    auto do_step = [&](int s, bool last, short8 (&bcur)[2][2], short8 (&bnxt)[2][2]) {
        const int b = s & 1;
        if (last) asm volatile("s_waitcnt vmcnt(0)" ::: "memory");
        else      asm volatile("s_waitcnt vmcnt(2)" ::: "memory");
        __builtin_amdgcn_sched_barrier(0);
        __builtin_amdgcn_s_barrier();
        __builtin_amdgcn_sched_barrier(0);
        if (!last) loadB(s + 1, bnxt);          // B prefetch, off critical path
        #pragma unroll
        for (int h = 0; h < 2; ++h) {
            #pragma unroll
            for (int i = 0; i < 8; ++i) {
                int r = i * 16 + l15;
                short8 a = *(const short8*)&As[b][r * 128 + (((lg + 4 * h) ^ (r & 7)) << 4)];
                acc[i][0] = __builtin_amdgcn_mfma_f32_16x16x32_bf16(a, bcur[h][0], acc[i][0], 0, 0, 0);
                acc[i][1] = __builtin_amdgcn_mfma_f32_16x16x32_bf16(a, bcur[h][1], acc[i][1], 0, 0, 0);
            }
        }
        __builtin_amdgcn_sched_barrier(0);
        __builtin_amdgcn_s_barrier();           // all waves done reading As[b]
        __builtin_amdgcn_sched_barrier(0);
        if (s + 2 < nsteps) stage(s + 2, b);
    };

    short8 b0[2][2], b1[2][2];
    loadB(0, b0);
    stage(0, 0);
    stage(1, 1);
    #pragma unroll
    for (int s = 0; s < nsteps; s += 2) {
        do_step(s,     s == nsteps - 1, b0, b1);
        do_step(s + 1, s + 1 == nsteps - 1, b1, b0);
    }

    if (SAGE) {
        // Epilogue: two 64-row halves through the 32KB LDS, coalesced stores
        __hip_bfloat16* lo = (__hip_bfloat16*)As;
        #pragma unroll
        for (int hh = 0; hh < 2; ++hh) {
            #pragma unroll
            for (int n = 0; n < 2; ++n) {
                int c = w * 32 + n * 16 + l15;
                float bv = bias[c];
                #pragma unroll
                for (int i2 = 0; i2 < 4; ++i2) {
                    int i = hh * 4 + i2;
                    #pragma unroll
                    for (int r = 0; r < 4; ++r) {
                        int rl = i2 * 16 + lg * 4 + r;
                        lo[rl * 256 + c] = __float2bfloat16(fmaxf(acc[i][n][r] + bv, 0.0f));
                    }
                }
            }
            __syncthreads();
            #pragma unroll
            for (int q = 0; q < 4; ++q) {
                int chunk = tid + q * 512;      // 2048 x 16B = 64 rows x 512B
                int rl = chunk >> 5, cc = chunk & 31;
                int grow = row0 + hh * 64 + rl;
                if (grow < N_NODES)
                    *(uint4*)((char*)Out + (size_t)grow * 512 + cc * 16) =
                        *(const uint4*)((const char*)As + rl * 512 + cc * 16);
            }
            __syncthreads();
        }
    } else {
        #pragma unroll
        for (int i = 0; i < 8; ++i) {
            float p[4];
            #pragma unroll
            for (int r = 0; r < 4; ++r) p[r] = 0.0f;
            #pragma unroll
            for (int n = 0; n < 2; ++n) {
                int c = w * 32 + n * 16 + l15;
                float bv = bias[c];
                float wv = W1[c];
                #pragma unroll
                for (int r = 0; r < 4; ++r)
                    p[r] += fmaxf(acc[i][n][r] + bv, 0.0f) * wv;
            }
            #pragma unroll
            for (int r = 0; r < 4; ++r) {
                float s = p[r];
                #pragma unroll
                for (int m = 1; m < 16; m <<= 1) s += __shfl_xor(s, m, 64);
                if (l15 == 0) {
                    int row = row0 + i * 16 + lg * 4 + r;
                    if (row < N_NODES) atomicAdd(&Pred[row], s);
                }
            }
        }
    }
}

extern "C" void kernel_launch(void* const* d_in, const int* in_sizes, int n_in,
                              void* d_out, int out_size, void* d_ws, size_t ws_size,
                              hipStream_t stream) {
    const float* node_attr = (const float*)d_in[0];
    const float* y         = (const float*)d_in[1];
    const float* node_emb  = (const float*)d_in[2];
    const float* net_W     = (const float*)d_in[4];
    const float* net_b     = (const float*)d_in[5];
    const float* dev_W     = (const float*)d_in[6];
    const float* dev_b     = (const float*)d_in[7];
    const float* pin_emb   = (const float*)d_in[8];
    const float* sage_Wl   = (const float*)d_in[9];
    const float* sage_bl   = (const float*)d_in[10];
    const float* sage_Wr   = (const float*)d_in[11];
    const float* head_W0   = (const float*)d_in[12];
    const float* head_b0   = (const float*)d_in[13];
    const float* head_W1   = (const float*)d_in[14];
    const float* head_b1   = (const float*)d_in[15];
    const int*   node_type = (const int*)d_in[16];
    const int*   edge_idx  = (const int*)d_in[18];
    float* out = (float*)d_out;

    const size_t xelems = (size_t)N_NODES * HID;
    char* p = (char*)d_ws;
    __hip_bfloat16* x0  = (__hip_bfloat16*)p;  p += xelems * 2;
    __hip_bfloat16* x1  = (__hip_bfloat16*)p;  p += xelems * 2;
    __hip_bfloat16* agg = (__hip_bfloat16*)p;  p += xelems * 2;
    __hip_bfloat16* Wt  = (__hip_bfloat16*)p;  p += (size_t)3 * 256 * 512 * 2;
    __hip_bfloat16* Wh  = (__hip_bfloat16*)p;  p += (size_t)256 * 256 * 2;
    int* deg    = (int*)p; p += N_NODES * 4;
    int* off    = (int*)p; p += N_NODES * 4;
    int* cursor = (int*)p; p += N_NODES * 4;
    int* slots  = (int*)p; p += N_EDGES * 4;
    int* total  = (int*)p; p += 16;

    k_prep<<<(3 * 131072 + 65536 + 255) / 256, 256, 0, stream>>>(
        sage_Wl, sage_Wr, head_W0, Wt, Wh, deg, total);
    k_init<<<(N_NODES * 33 + 255) / 256, 256, 0, stream>>>(
        node_attr, node_emb, net_W, net_b, dev_W, dev_b, pin_emb, node_type,
        y, head_b1, out, x0);
    k_hist<<<(N_EDGES + 255) / 256, 256, 0, stream>>>(edge_idx, deg);
    k_alloc<<<(N_NODES + 255) / 256, 256, 0, stream>>>(deg, off, cursor, total);
    k_fill<<<(N_EDGES + 255) / 256, 256, 0, stream>>>(edge_idx, cursor, slots);

    const int gemm_grid = (N_NODES + 127) / 128;
    __hip_bfloat16* xcur = x0;
    __hip_bfloat16* xalt = x1;
    for (int l = 0; l < NLAYERS; ++l) {
        k_aggregate<<<(N_NODES / 4 * 64 + 255) / 256, 256, 0, stream>>>(
            xcur, off, deg, slots, agg);
        k_mfma<true><<<gemm_grid, 512, 0, stream>>>(
            agg, xcur, Wt + (size_t)l * 131072,
            sage_bl + (size_t)l * HID, nullptr, xalt, nullptr);
        __hip_bfloat16* t = xcur; xcur = xalt; xalt = t;
    }
    k_mfma<false><<<gemm_grid, 512, 0, stream>>>(
        xcur, xcur, Wh, head_b0, head_W1, nullptr, out);
}